// Round 12
// baseline (263.532 us; speedup 1.0000x reference)
//
#include <hip/hip_runtime.h>
#include <hip/hip_bf16.h>
#include <stdint.h>

#define SEQ 4096
#define EMB 1024
#define HD  64
#define NB  4

typedef __attribute__((ext_vector_type(8))) short short8;   // 8 x bf16 (4 VGPRs)
typedef __attribute__((ext_vector_type(4))) float f32x4;
typedef __attribute__((ext_vector_type(4))) unsigned int uint4v;

// RNE float -> bf16 bits (no NaN inputs here)
static __device__ __forceinline__ unsigned short f2bf(float f) {
    unsigned int u = __float_as_uint(f);
    u += 0x7fffu + ((u >> 16) & 1u);
    return (unsigned short)(u >> 16);
}

// keepalive: forces the full 16B load to stay, emits nothing
static __device__ __forceinline__ void keep4(const short8& v) {
    uint4v u;
    __builtin_memcpy(&u, &v, 16);
    asm volatile("" :: "v"(u[0]), "v"(u[1]), "v"(u[2]), "v"(u[3]));
}

// ---------------------------------------------------------------------------
// Prep: Wt[m][d][e] = bf16(W_m[e][d]),  m in {q,k,v}.  3*64*1024 elements.
// Wq is pre-scaled by log2(e)/sqrt(64) so attn needs no scale multiply.
// ---------------------------------------------------------------------------
__global__ __launch_bounds__(256) void wprep_kernel(
        const float* __restrict__ Wq, const float* __restrict__ Wk,
        const float* __restrict__ Wv, unsigned short* __restrict__ Wt) {
    int idx = blockIdx.x * 256 + threadIdx.x;       // < 3*65536
    int m = idx >> 16;
    int r = idx & 65535;
    int d = r >> 10;
    int e = r & 1023;
    const float* W = (m == 0) ? Wq : (m == 1) ? Wk : Wv;
    float v = W[e * HD + d];
    if (m == 0) v *= 0.18033688011111793f;          // log2(e)/sqrt(64)
    Wt[idx] = f2bf(v);
}

// ---------------------------------------------------------------------------
// QKV projection (unchanged from R11): 32-row blocks, fused m, 4-wave K-split.
// V stored chunked: Vt[b][chunk=s>>6][d][64]; in-chunk col p=(s&32)|sigma(t).
// ---------------------------------------------------------------------------
__global__ __launch_bounds__(256, 2) void qkv_kernel(
        const float* __restrict__ H, const unsigned short* __restrict__ Wt,
        unsigned short* __restrict__ Qb, unsigned short* __restrict__ Kb,
        unsigned short* __restrict__ Vt) {
    __shared__ float lds_red[2][32][192];   // 48 KB
    const int tid  = threadIdx.x;
    const int wid  = tid >> 6;
    const int lane = tid & 63;
    const int lr = lane & 15, lg = lane >> 4;
    const int rowbase = blockIdx.x * 32;

    const float* __restrict__ a0p = H + (size_t)(rowbase + lr) * EMB + wid * 256 + lg * 8;
    const float* __restrict__ a1p = a0p + 16 * EMB;
    const unsigned short* __restrict__ wb = Wt + wid * 256 + lg * 8;

    f32x4 acc[2][3][4];
    #pragma unroll
    for (int rt = 0; rt < 2; ++rt)
        #pragma unroll
        for (int m = 0; m < 3; ++m)
            #pragma unroll
            for (int nt = 0; nt < 4; ++nt)
                acc[rt][m][nt] = f32x4{0.f, 0.f, 0.f, 0.f};

    f32x4 hA0, hA1, hA2, hA3, hB0, hB1, hB2, hB3;

    auto compute_step = [&](f32x4& h0, f32x4& h1, f32x4& h2, f32x4& h3, int kk) {
        short8 af0, af1;
        #pragma unroll
        for (int j = 0; j < 4; ++j) {
            af0[j]     = (short)f2bf(h0[j]);
            af0[4 + j] = (short)f2bf(h1[j]);
            af1[j]     = (short)f2bf(h2[j]);
            af1[4 + j] = (short)f2bf(h3[j]);
        }
        #pragma unroll
        for (int m = 0; m < 3; ++m) {
            #pragma unroll
            for (int nt = 0; nt < 4; ++nt) {
                short8 bf_ = *(const short8*)(wb + m * 65536 + (nt * 16 + lr) * EMB + kk);
                acc[0][m][nt] = __builtin_amdgcn_mfma_f32_16x16x32_bf16(af0, bf_, acc[0][m][nt], 0, 0, 0);
                acc[1][m][nt] = __builtin_amdgcn_mfma_f32_16x16x32_bf16(af1, bf_, acc[1][m][nt], 0, 0, 0);
            }
        }
    };

    hA0 = *(const f32x4*)(a0p);  hA1 = *(const f32x4*)(a0p + 4);
    hA2 = *(const f32x4*)(a1p);  hA3 = *(const f32x4*)(a1p + 4);

    #pragma unroll
    for (int kko = 0; kko < 4; ++kko) {
        const int kk = kko * 64;
        hB0 = *(const f32x4*)(a0p + kk + 32);  hB1 = *(const f32x4*)(a0p + kk + 36);
        hB2 = *(const f32x4*)(a1p + kk + 32);  hB3 = *(const f32x4*)(a1p + kk + 36);
        compute_step(hA0, hA1, hA2, hA3, kk);
        if (kko < 3) {
            hA0 = *(const f32x4*)(a0p + kk + 64);  hA1 = *(const f32x4*)(a0p + kk + 68);
            hA2 = *(const f32x4*)(a1p + kk + 64);  hA3 = *(const f32x4*)(a1p + kk + 68);
        }
        compute_step(hB0, hB1, hB2, hB3, kk + 32);
    }

    if (wid >= 2) {
        #pragma unroll
        for (int rt = 0; rt < 2; ++rt)
            #pragma unroll
            for (int m = 0; m < 3; ++m)
                #pragma unroll
                for (int nt = 0; nt < 4; ++nt)
                    #pragma unroll
                    for (int r = 0; r < 4; ++r)
                        lds_red[wid - 2][rt * 16 + lg * 4 + r][m * 64 + nt * 16 + lr] = acc[rt][m][nt][r];
    }
    __syncthreads();
    if (wid < 2) {
        #pragma unroll
        for (int rt = 0; rt < 2; ++rt)
            #pragma unroll
            for (int m = 0; m < 3; ++m)
                #pragma unroll
                for (int nt = 0; nt < 4; ++nt)
                    #pragma unroll
                    for (int r = 0; r < 4; ++r)
                        acc[rt][m][nt][r] += lds_red[wid][rt * 16 + lg * 4 + r][m * 64 + nt * 16 + lr];
    }
    __syncthreads();
    if (wid == 1) {
        #pragma unroll
        for (int rt = 0; rt < 2; ++rt)
            #pragma unroll
            for (int m = 0; m < 3; ++m)
                #pragma unroll
                for (int nt = 0; nt < 4; ++nt)
                    #pragma unroll
                    for (int r = 0; r < 4; ++r)
                        lds_red[0][rt * 16 + lg * 4 + r][m * 64 + nt * 16 + lr] = acc[rt][m][nt][r];
    }
    __syncthreads();
    if (wid == 0) {
        #pragma unroll
        for (int rt = 0; rt < 2; ++rt)
            #pragma unroll
            for (int m = 0; m < 3; ++m)
                #pragma unroll
                for (int nt = 0; nt < 4; ++nt)
                    #pragma unroll
                    for (int r = 0; r < 4; ++r) {
                        int row = rt * 16 + lg * 4 + r;
                        int col = m * 64 + nt * 16 + lr;
                        lds_red[0][row][col] += acc[rt][m][nt][r];
                    }
    }
    __syncthreads();

    {
        const int row = tid >> 3;            // 0..31
        const int d0  = (tid & 7) * 8;       // 0,8,...,56
        const size_t grow = (size_t)(rowbase + row);
        short8 uq, uk;
        #pragma unroll
        for (int j = 0; j < 8; ++j) {
            uq[j] = (short)f2bf(lds_red[0][row][d0 + j]);
            uk[j] = (short)f2bf(lds_red[0][row][64 + d0 + j]);
        }
        *(short8*)(Qb + grow * HD + d0) = uq;
        *(short8*)(Kb + grow * HD + d0) = uk;
    }
    {
        const int d  = tid >> 2;             // 0..63
        const int j  = tid & 3;
        const int b  = rowbase >> 12;
        const int sl = rowbase & (SEQ - 1);
        unsigned short* vrow = Vt + (((size_t)b * 64 + (sl >> 6)) * 64 + d) * 64 + (sl & 32);
        #pragma unroll
        for (int k4 = 0; k4 < 4; ++k4) {
            int t0 = j * 2 + k4 * 8;         // even t in 0..30
            int p0 = ((t0 & 12) << 1) | (t0 & 3) | ((t0 & 16) >> 2);
            unsigned int val = (unsigned int)f2bf(lds_red[0][t0][128 + d])
                             | ((unsigned int)f2bf(lds_red[0][t0 + 1][128 + d]) << 16);
            *(unsigned int*)(vrow + p0) = val;
        }
    }
}

// ---------------------------------------------------------------------------
// Flash attention — ABLATION TEMPLATE.
// MODE 0: full kernel (real output; launched LAST).
// MODE 1: compute-only — loads hoisted out of loop (XOR-perturbed vs
//         invariant-hoisting); full softmax+MFMA chain. No per-iter memory.
// MODE 2: memory+MFMA — loads + QK + cvt_pk + PV; no mask/max/exp VALU.
// MODE 3: memory-only — loads + asm keepalive; no MFMA, no softmax.
// All modes: same grid/mapping/trip counts/epilogue; write to `out`
// (MODE 0 overwrites last -> harness validates correct values).
// ---------------------------------------------------------------------------
template <int MODE>
__global__ __launch_bounds__(512, 4) void attn_kernel(
        const unsigned short* __restrict__ Qb, const unsigned short* __restrict__ Kb,
        const unsigned short* __restrict__ Vt, float* __restrict__ out) {
    __shared__ float lds_o[8][16][65];     // 33.3 KB partials (padded)
    __shared__ float lds_ml[8][4][16][2];  // 4 KB per-(wave,lanegroup) m,l
    const int tid  = threadIdx.x;
    const int w    = tid >> 6;
    const int lane = tid & 63;
    const int lr = lane & 15, lg = lane >> 4;

    const int bid  = blockIdx.x;
    const int xcd  = bid & 7;
    const int slot = bid >> 3;
    const int b    = xcd & 3;
    const int pz   = slot & 31, hh = slot >> 5;
    const int qtl  = (hh << 5) | ((hh & 1) ? (31 - pz) : pz);
    const int qt   = (qtl << 1) | (xcd >> 2);
    const int qbase = qt * 16;

    const unsigned short* __restrict__ Qp = Qb + ((size_t)b * SEQ + qbase) * HD;
    const unsigned short* __restrict__ Kp = Kb + (size_t)b * SEQ * HD;
    const unsigned short* __restrict__ Vp = Vt + (size_t)b * (SEQ / 64) * HD * 64;

    short8 qf0 = *(const short8*)(Qp + lr * HD +      lg * 8);
    short8 qf1 = *(const short8*)(Qp + lr * HD + 32 + lg * 8);

    f32x4 o[4];
    #pragma unroll
    for (int nt = 0; nt < 4; ++nt) o[nt] = f32x4{0.f, 0.f, 0.f, 0.f};
    float mrun = 0.f;
    float lrun = 0.f;

    const int total64 = (qbase + 79) >> 6;

    // MODE 1: preload one chunk (chunk index w <= 7, always in-bounds)
    short8 c_k00, c_k01, c_k10, c_k11, c_k20, c_k21, c_k30, c_k31;
    short8 c_v00, c_v01, c_v10, c_v11, c_v20, c_v21, c_v30, c_v31;
    if constexpr (MODE == 1) {
        const unsigned short* kp = Kp + (size_t)(w * 64 + lr) * HD + lg * 8;
        const unsigned short* vp = Vp + ((size_t)w * 64 + lr) * 64 + lg * 8;
        c_k00 = *(const short8*)(kp);             c_k01 = *(const short8*)(kp + 32);
        c_k10 = *(const short8*)(kp + 16 * HD);   c_k11 = *(const short8*)(kp + 16 * HD + 32);
        c_k20 = *(const short8*)(kp + 32 * HD);   c_k21 = *(const short8*)(kp + 32 * HD + 32);
        c_k30 = *(const short8*)(kp + 48 * HD);   c_k31 = *(const short8*)(kp + 48 * HD + 32);
        c_v00 = *(const short8*)(vp);             c_v01 = *(const short8*)(vp + 32);
        c_v10 = *(const short8*)(vp + 16 * 64);   c_v11 = *(const short8*)(vp + 16 * 64 + 32);
        c_v20 = *(const short8*)(vp + 32 * 64);   c_v21 = *(const short8*)(vp + 32 * 64 + 32);
        c_v30 = *(const short8*)(vp + 48 * 64);   c_v31 = *(const short8*)(vp + 48 * 64 + 32);
    }

    for (int it = w; it < total64; it += 8) {
        const int kvb = it * 64;
        short8 k00, k01, k10, k11, k20, k21, k30, k31;
        short8 vf00, vf01, vf10, vf11, vf20, vf21, vf30, vf31;

        if constexpr (MODE == 1) {
            k00 = c_k00; k01 = c_k01; k10 = c_k10; k11 = c_k11;
            k20 = c_k20; k21 = c_k21; k30 = c_k30; k31 = c_k31;
            vf00 = c_v00; vf01 = c_v01; vf10 = c_v10; vf11 = c_v11;
            vf20 = c_v20; vf21 = c_v21; vf30 = c_v30; vf31 = c_v31;
            k00[0] ^= (short)it;               // defeat loop-invariant hoisting
        } else {
            const unsigned short* kp = Kp + (size_t)(kvb + lr) * HD + lg * 8;
            const unsigned short* vp = Vp + ((size_t)it * 64 + lr) * 64 + lg * 8;
            k00 = *(const short8*)(kp);             k01 = *(const short8*)(kp + 32);
            k10 = *(const short8*)(kp + 16 * HD);   k11 = *(const short8*)(kp + 16 * HD + 32);
            k20 = *(const short8*)(kp + 32 * HD);   k21 = *(const short8*)(kp + 32 * HD + 32);
            k30 = *(const short8*)(kp + 48 * HD);   k31 = *(const short8*)(kp + 48 * HD + 32);
            vf00 = *(const short8*)(vp);            vf01 = *(const short8*)(vp + 32);
            vf10 = *(const short8*)(vp + 16 * 64);  vf11 = *(const short8*)(vp + 16 * 64 + 32);
            vf20 = *(const short8*)(vp + 32 * 64);  vf21 = *(const short8*)(vp + 32 * 64 + 32);
            vf30 = *(const short8*)(vp + 48 * 64);  vf31 = *(const short8*)(vp + 48 * 64 + 32);
        }

        if constexpr (MODE == 3) {
            keep4(k00); keep4(k01); keep4(k10); keep4(k11);
            keep4(k20); keep4(k21); keep4(k30); keep4(k31);
            keep4(vf00); keep4(vf01); keep4(vf10); keep4(vf11);
            keep4(vf20); keep4(vf21); keep4(vf30); keep4(vf31);
            continue;
        }

        f32x4 s0 = f32x4{0.f, 0.f, 0.f, 0.f};
        f32x4 s1 = f32x4{0.f, 0.f, 0.f, 0.f};
        f32x4 s2 = f32x4{0.f, 0.f, 0.f, 0.f};
        f32x4 s3 = f32x4{0.f, 0.f, 0.f, 0.f};
        s0 = __builtin_amdgcn_mfma_f32_16x16x32_bf16(k00, qf0, s0, 0, 0, 0);
        s0 = __builtin_amdgcn_mfma_f32_16x16x32_bf16(k01, qf1, s0, 0, 0, 0);
        s1 = __builtin_amdgcn_mfma_f32_16x16x32_bf16(k10, qf0, s1, 0, 0, 0);
        s1 = __builtin_amdgcn_mfma_f32_16x16x32_bf16(k11, qf1, s1, 0, 0, 0);
        s2 = __builtin_amdgcn_mfma_f32_16x16x32_bf16(k20, qf0, s2, 0, 0, 0);
        s2 = __builtin_amdgcn_mfma_f32_16x16x32_bf16(k21, qf1, s2, 0, 0, 0);
        s3 = __builtin_amdgcn_mfma_f32_16x16x32_bf16(k30, qf0, s3, 0, 0, 0);
        s3 = __builtin_amdgcn_mfma_f32_16x16x32_bf16(k31, qf1, s3, 0, 0, 0);

        short8 pba, pbb;
        if constexpr (MODE == 2) {
            uint4v ua, ub;
            asm("v_cvt_pk_bf16_f32 %0, %1, %2" : "=v"(ua[0]) : "v"(s0[0]), "v"(s0[1]));
            asm("v_cvt_pk_bf16_f32 %0, %1, %2" : "=v"(ua[1]) : "v"(s0[2]), "v"(s0[3]));
            asm("v_cvt_pk_bf16_f32 %0, %1, %2" : "=v"(ua[2]) : "v"(s1[0]), "v"(s1[1]));
            asm("v_cvt_pk_bf16_f32 %0, %1, %2" : "=v"(ua[3]) : "v"(s1[2]), "v"(s1[3]));
            asm("v_cvt_pk_bf16_f32 %0, %1, %2" : "=v"(ub[0]) : "v"(s2[0]), "v"(s2[1]));
            asm("v_cvt_pk_bf16_f32 %0, %1, %2" : "=v"(ub[1]) : "v"(s2[2]), "v"(s2[3]));
            asm("v_cvt_pk_bf16_f32 %0, %1, %2" : "=v"(ub[2]) : "v"(s3[0]), "v"(s3[1]));
            asm("v_cvt_pk_bf16_f32 %0, %1, %2" : "=v"(ub[3]) : "v"(s3[2]), "v"(s3[3]));
            pba = *(short8*)&ua;
            pbb = *(short8*)&ub;
        } else {
            if (kvb + 63 > qbase) {
                const int qg = qbase + lr;
                #pragma unroll
                for (int r = 0; r < 4; ++r) {
                    int ky = kvb + lg * 4 + r;
                    if (ky      > qg) s0[r] = -1e30f;
                    if (ky + 16 > qg) s1[r] = -1e30f;
                    if (ky + 32 > qg) s2[r] = -1e30f;
                    if (ky + 48 > qg) s3[r] = -1e30f;
                }
            }
            float m01 = fmaxf(fmaxf(s0[0], s0[1]), fmaxf(s0[2], s0[3]));
            float m23 = fmaxf(fmaxf(s1[0], s1[1]), fmaxf(s1[2], s1[3]));
            float m45 = fmaxf(fmaxf(s2[0], s2[1]), fmaxf(s2[2], s2[3]));
            float m67 = fmaxf(fmaxf(s3[0], s3[1]), fmaxf(s3[2], s3[3]));
            float mx = fmaxf(fmaxf(m01, m23), fmaxf(m45, m67));

            if (!__all(mx <= mrun + 8.f)) {
                float mnew = fmaxf(mrun, mx);
                float f = exp2f(mrun - mnew);
                mrun = mnew;
                lrun *= f;
                #pragma unroll
                for (int nt = 0; nt < 4; ++nt) o[nt] *= f;
            }

            float p0[4], p1[4], p2[4], p3[4];
            #pragma unroll
            for (int r = 0; r < 4; ++r) {
                p0[r] = exp2f(s0[r] - mrun);
                p1[r] = exp2f(s1[r] - mrun);
                p2[r] = exp2f(s2[r] - mrun);
                p3[r] = exp2f(s3[r] - mrun);
            }
            lrun += ((p0[0] + p0[1]) + (p0[2] + p0[3])) + ((p1[0] + p1[1]) + (p1[2] + p1[3]))
                  + ((p2[0] + p2[1]) + (p2[2] + p2[3])) + ((p3[0] + p3[1]) + (p3[2] + p3[3]));

            uint4v ua, ub;
            asm("v_cvt_pk_bf16_f32 %0, %1, %2" : "=v"(ua[0]) : "v"(p0[0]), "v"(p0[1]));
            asm("v_cvt_pk_bf16_f32 %0, %1, %2" : "=v"(ua[1]) : "v"(p0[2]), "v"(p0[3]));
            asm("v_cvt_pk_bf16_f32 %0, %1, %2" : "=v"(ua[2]) : "v"(p1[0]), "v"(p1[1]));
            asm("v_cvt_pk_bf16_f32 %0, %1, %2" : "=v"(ua[3]) : "v"(p1[2]), "v"(p1[3]));
            asm("v_cvt_pk_bf16_f32 %0, %1, %2" : "=v"(ub[0]) : "v"(p2[0]), "v"(p2[1]));
            asm("v_cvt_pk_bf16_f32 %0, %1, %2" : "=v"(ub[1]) : "v"(p2[2]), "v"(p2[3]));
            asm("v_cvt_pk_bf16_f32 %0, %1, %2" : "=v"(ub[2]) : "v"(p3[0]), "v"(p3[1]));
            asm("v_cvt_pk_bf16_f32 %0, %1, %2" : "=v"(ub[3]) : "v"(p3[2]), "v"(p3[3]));
            pba = *(short8*)&ua;
            pbb = *(short8*)&ub;
        }

        o[0] = __builtin_amdgcn_mfma_f32_16x16x32_bf16(vf00, pba, o[0], 0, 0, 0);
        o[1] = __builtin_amdgcn_mfma_f32_16x16x32_bf16(vf10, pba, o[1], 0, 0, 0);
        o[2] = __builtin_amdgcn_mfma_f32_16x16x32_bf16(vf20, pba, o[2], 0, 0, 0);
        o[3] = __builtin_amdgcn_mfma_f32_16x16x32_bf16(vf30, pba, o[3], 0, 0, 0);
        o[0] = __builtin_amdgcn_mfma_f32_16x16x32_bf16(vf01, pbb, o[0], 0, 0, 0);
        o[1] = __builtin_amdgcn_mfma_f32_16x16x32_bf16(vf11, pbb, o[1], 0, 0, 0);
        o[2] = __builtin_amdgcn_mfma_f32_16x16x32_bf16(vf21, pbb, o[2], 0, 0, 0);
        o[3] = __builtin_amdgcn_mfma_f32_16x16x32_bf16(vf31, pbb, o[3], 0, 0, 0);
    }

    // ---- shared epilogue (all modes): merge 8x4 partials, write out
    #pragma unroll
    for (int nt = 0; nt < 4; ++nt)
        #pragma unroll
        for (int r = 0; r < 4; ++r)
            lds_o[w][lr][nt * 16 + lg * 4 + r] = o[nt][r];
    lds_ml[w][lg][lr][0] = mrun;
    lds_ml[w][lg][lr][1] = lrun;
    __syncthreads();

    const int row = tid >> 5;
    const int c2  = (tid & 31) * 2;
    const int lgc = (c2 >> 2) & 3;
    float M = -1e30f;
    #pragma unroll
    for (int ww = 0; ww < 8; ++ww)
        #pragma unroll
        for (int g = 0; g < 4; ++g)
            M = fmaxf(M, lds_ml[ww][g][row][0]);
    float L = 0.f, a0 = 0.f, a1 = 0.f;
    #pragma unroll
    for (int ww = 0; ww < 8; ++ww) {
        #pragma unroll
        for (int g = 0; g < 4; ++g)
            L += exp2f(lds_ml[ww][g][row][0] - M) * lds_ml[ww][g][row][1];
        float wt = exp2f(lds_ml[ww][lgc][row][0] - M);
        a0 += wt * lds_o[ww][row][c2];
        a1 += wt * lds_o[ww][row][c2 + 1];
    }
    float invL = 1.0f / L;
    float2 res;
    res.x = a0 * invL;
    res.y = a1 * invL;
    *(float2*)(out + ((size_t)b * SEQ + qbase + row) * HD + c2) = res;
}

// ---------------------------------------------------------------------------
extern "C" void kernel_launch(void* const* d_in, const int* in_sizes, int n_in,
                              void* d_out, int out_size, void* d_ws, size_t ws_size,
                              hipStream_t stream) {
    const float* H  = (const float*)d_in[0];
    const float* Wq = (const float*)d_in[1];
    const float* Wk = (const float*)d_in[2];
    const float* Wv = (const float*)d_in[3];
    float* out = (float*)d_out;

    unsigned short* Qb = (unsigned short*)d_ws;
    unsigned short* Kb = Qb + (size_t)NB * SEQ * HD;
    unsigned short* Vt = Kb + (size_t)NB * SEQ * HD;
    unsigned short* Wt = Vt + (size_t)NB * SEQ * HD;

    wprep_kernel<<<768, 256, 0, stream>>>(Wq, Wk, Wv, Wt);
    qkv_kernel<<<NB * SEQ / 32, 256, 0, stream>>>(H, Wt, Qb, Kb, Vt);
    // ablation dispatches (outputs overwritten by the final MODE 0 run)
    attn_kernel<3><<<NB * (SEQ / 16), 512, 0, stream>>>(Qb, Kb, Vt, out);
    attn_kernel<2><<<NB * (SEQ / 16), 512, 0, stream>>>(Qb, Kb, Vt, out);
    attn_kernel<1><<<NB * (SEQ / 16), 512, 0, stream>>>(Qb, Kb, Vt, out);
    // the real kernel — runs last, produces the validated output
    attn_kernel<0><<<NB * (SEQ / 16), 512, 0, stream>>>(Qb, Kb, Vt, out);
}

// Round 15
// 88.638 us; speedup vs baseline: 2.9731x; 2.9731x over previous
//
#include <hip/hip_runtime.h>
#include <hip/hip_bf16.h>
#include <stdint.h>

#define SEQ 4096
#define EMB 1024
#define HD  64
#define NB  4

typedef __attribute__((ext_vector_type(8))) short short8;   // 8 x bf16 (4 VGPRs)
typedef __attribute__((ext_vector_type(4))) float f32x4;
typedef __attribute__((ext_vector_type(4))) unsigned int uint4v;

// RNE float -> bf16 bits (no NaN inputs here)
static __device__ __forceinline__ unsigned short f2bf(float f) {
    unsigned int u = __float_as_uint(f);
    u += 0x7fffu + ((u >> 16) & 1u);
    return (unsigned short)(u >> 16);
}

// ---------------------------------------------------------------------------
// Prep: Wt[m][d][e] = bf16(W_m[e][d]),  m in {q,k,v}.  3*64*1024 elements.
// Wq is pre-scaled by log2(e)/sqrt(64) so attn needs no scale multiply.
// ---------------------------------------------------------------------------
__global__ __launch_bounds__(256) void wprep_kernel(
        const float* __restrict__ Wq, const float* __restrict__ Wk,
        const float* __restrict__ Wv, unsigned short* __restrict__ Wt) {
    int idx = blockIdx.x * 256 + threadIdx.x;       // < 3*65536
    int m = idx >> 16;
    int r = idx & 65535;
    int d = r >> 10;
    int e = r & 1023;
    const float* W = (m == 0) ? Wq : (m == 1) ? Wk : Wv;
    float v = W[e * HD + d];
    if (m == 0) v *= 0.18033688011111793f;          // log2(e)/sqrt(64)
    Wt[idx] = f2bf(v);
}

// ---------------------------------------------------------------------------
// QKV projection (structure unchanged). Swizzles for the LDS-cooperative attn
// (rule #21: permute at creation, read swizzled):
//  - Kb rows store column-XOR swizzled:  elem d -> d ^ ((row&7)<<3)
//  - Vt chunked [b][chunk][d][64] rows likewise: col e -> e ^ ((d&7)<<3),
//    with e = (s&32) | sigma(t), sigma(t) = ((t&12)<<1)|(t&3)|((t&16)>>2).
// Qb stays unswizzled (attn reads Q from global directly).
// ---------------------------------------------------------------------------
__global__ __launch_bounds__(256, 2) void qkv_kernel(
        const float* __restrict__ H, const unsigned short* __restrict__ Wt,
        unsigned short* __restrict__ Qb, unsigned short* __restrict__ Kb,
        unsigned short* __restrict__ Vt) {
    __shared__ float lds_red[2][32][192];   // 48 KB
    const int tid  = threadIdx.x;
    const int wid  = tid >> 6;
    const int lane = tid & 63;
    const int lr = lane & 15, lg = lane >> 4;
    const int rowbase = blockIdx.x * 32;

    const float* __restrict__ a0p = H + (size_t)(rowbase + lr) * EMB + wid * 256 + lg * 8;
    const float* __restrict__ a1p = a0p + 16 * EMB;
    const unsigned short* __restrict__ wb = Wt + wid * 256 + lg * 8;

    f32x4 acc[2][3][4];
    #pragma unroll
    for (int rt = 0; rt < 2; ++rt)
        #pragma unroll
        for (int m = 0; m < 3; ++m)
            #pragma unroll
            for (int nt = 0; nt < 4; ++nt)
                acc[rt][m][nt] = f32x4{0.f, 0.f, 0.f, 0.f};

    f32x4 hA0, hA1, hA2, hA3, hB0, hB1, hB2, hB3;

    auto compute_step = [&](f32x4& h0, f32x4& h1, f32x4& h2, f32x4& h3, int kk) {
        short8 af0, af1;
        #pragma unroll
        for (int j = 0; j < 4; ++j) {
            af0[j]     = (short)f2bf(h0[j]);
            af0[4 + j] = (short)f2bf(h1[j]);
            af1[j]     = (short)f2bf(h2[j]);
            af1[4 + j] = (short)f2bf(h3[j]);
        }
        #pragma unroll
        for (int m = 0; m < 3; ++m) {
            #pragma unroll
            for (int nt = 0; nt < 4; ++nt) {
                short8 bf_ = *(const short8*)(wb + m * 65536 + (nt * 16 + lr) * EMB + kk);
                acc[0][m][nt] = __builtin_amdgcn_mfma_f32_16x16x32_bf16(af0, bf_, acc[0][m][nt], 0, 0, 0);
                acc[1][m][nt] = __builtin_amdgcn_mfma_f32_16x16x32_bf16(af1, bf_, acc[1][m][nt], 0, 0, 0);
            }
        }
    };

    hA0 = *(const f32x4*)(a0p);  hA1 = *(const f32x4*)(a0p + 4);
    hA2 = *(const f32x4*)(a1p);  hA3 = *(const f32x4*)(a1p + 4);

    #pragma unroll
    for (int kko = 0; kko < 4; ++kko) {
        const int kk = kko * 64;
        hB0 = *(const f32x4*)(a0p + kk + 32);  hB1 = *(const f32x4*)(a0p + kk + 36);
        hB2 = *(const f32x4*)(a1p + kk + 32);  hB3 = *(const f32x4*)(a1p + kk + 36);
        compute_step(hA0, hA1, hA2, hA3, kk);
        if (kko < 3) {
            hA0 = *(const f32x4*)(a0p + kk + 64);  hA1 = *(const f32x4*)(a0p + kk + 68);
            hA2 = *(const f32x4*)(a1p + kk + 64);  hA3 = *(const f32x4*)(a1p + kk + 68);
        }
        compute_step(hB0, hB1, hB2, hB3, kk + 32);
    }

    if (wid >= 2) {
        #pragma unroll
        for (int rt = 0; rt < 2; ++rt)
            #pragma unroll
            for (int m = 0; m < 3; ++m)
                #pragma unroll
                for (int nt = 0; nt < 4; ++nt)
                    #pragma unroll
                    for (int r = 0; r < 4; ++r)
                        lds_red[wid - 2][rt * 16 + lg * 4 + r][m * 64 + nt * 16 + lr] = acc[rt][m][nt][r];
    }
    __syncthreads();
    if (wid < 2) {
        #pragma unroll
        for (int rt = 0; rt < 2; ++rt)
            #pragma unroll
            for (int m = 0; m < 3; ++m)
                #pragma unroll
                for (int nt = 0; nt < 4; ++nt)
                    #pragma unroll
                    for (int r = 0; r < 4; ++r)
                        acc[rt][m][nt][r] += lds_red[wid][rt * 16 + lg * 4 + r][m * 64 + nt * 16 + lr];
    }
    __syncthreads();
    if (wid == 1) {
        #pragma unroll
        for (int rt = 0; rt < 2; ++rt)
            #pragma unroll
            for (int m = 0; m < 3; ++m)
                #pragma unroll
                for (int nt = 0; nt < 4; ++nt)
                    #pragma unroll
                    for (int r = 0; r < 4; ++r)
                        lds_red[0][rt * 16 + lg * 4 + r][m * 64 + nt * 16 + lr] = acc[rt][m][nt][r];
    }
    __syncthreads();
    if (wid == 0) {
        #pragma unroll
        for (int rt = 0; rt < 2; ++rt)
            #pragma unroll
            for (int m = 0; m < 3; ++m)
                #pragma unroll
                for (int nt = 0; nt < 4; ++nt)
                    #pragma unroll
                    for (int r = 0; r < 4; ++r) {
                        int row = rt * 16 + lg * 4 + r;
                        int col = m * 64 + nt * 16 + lr;
                        lds_red[0][row][col] += acc[rt][m][nt][r];
                    }
    }
    __syncthreads();

    {
        const int row = tid >> 3;            // 0..31
        const int d0  = (tid & 7) * 8;       // 0,8,...,56
        const size_t grow = (size_t)(rowbase + row);
        short8 uq, uk;
        #pragma unroll
        for (int j = 0; j < 8; ++j) {
            uq[j] = (short)f2bf(lds_red[0][row][d0 + j]);
            uk[j] = (short)f2bf(lds_red[0][row][64 + d0 + j]);
        }
        *(short8*)(Qb + grow * HD + d0) = uq;
        // K: column-XOR swizzle keyed by row&7 (grow&7 == row&7, rowbase%32==0)
        *(short8*)(Kb + grow * HD + (d0 ^ ((row & 7) << 3))) = uk;
    }
    {
        const int d  = tid >> 2;             // 0..63
        const int j  = tid & 3;
        const int b  = rowbase >> 12;
        const int sl = rowbase & (SEQ - 1);
        unsigned short* vrow = Vt + (((size_t)b * 64 + (sl >> 6)) * 64 + d) * 64;
        const int dsw = (d & 7) << 3;
        #pragma unroll
        for (int k4 = 0; k4 < 4; ++k4) {
            int t0 = j * 2 + k4 * 8;         // even t in 0..30
            int p0 = ((t0 & 12) << 1) | (t0 & 3) | ((t0 & 16) >> 2);
            int e  = ((sl & 32) | p0) ^ dsw; // row-swizzled column (pair-aligned)
            unsigned int val = (unsigned int)f2bf(lds_red[0][t0][128 + d])
                             | ((unsigned int)f2bf(lds_red[0][t0 + 1][128 + d]) << 16);
            *(unsigned int*)(vrow + e) = val;
        }
    }
}

// ---------------------------------------------------------------------------
// Flash attention, LDS-COOPERATIVE (R13 structure, MASK-BOUND FIX).
// Block = 8 waves x 16 q-rows = 128 q-rows; per 64-key chunk the block stages
// K(8KB)+V(8KB) into LDS with two global_load_lds(16B) per wave; all 8 waves
// consume the same tiles -> 8x fewer global load instructions.
// Softmax fixed m=0 (scores << overflow): p = exp2(s); exact merge.
// MASK FIX: mask whenever chunk extends beyond the wave's FIRST row
// (kvb + 63 > qrow0), NOT its last row — R13 leaked up to 15 future keys
// into low-l rows (absmax 0.155).
// Causal balance: 2 K-slices per q-block (equal qb+1 chunks each);
// partial (o,l) per slice summed by merge_kernel.
// ---------------------------------------------------------------------------
__global__ __launch_bounds__(512, 2) void attn_kernel(
        const unsigned short* __restrict__ Qb, const unsigned short* __restrict__ Kb,
        const unsigned short* __restrict__ Vt,
        float* __restrict__ part_o, float* __restrict__ part_l) {
    __shared__ unsigned short ldsK[64 * 64];   // 8 KB (swizzled image)
    __shared__ unsigned short ldsV[64 * 64];   // 8 KB (swizzled image)
    const int tid  = threadIdx.x;
    const int w    = tid >> 6;
    const int lane = tid & 63;
    const int lr = lane & 15, lg = lane >> 4;

    const int bid   = blockIdx.x;
    const int b     = bid & 3;
    const int qb    = (bid >> 2) & 31;
    const int slice = bid >> 7;                // 0 or 1
    const int qrow0 = qb * 128 + w * 16;       // this wave's 16 q-rows
    const int qwmax = qrow0 + 15;

    const unsigned short* __restrict__ Kp = Kb + (size_t)b * SEQ * HD;
    const unsigned short* __restrict__ Vp = Vt + (size_t)b * 64 * 4096;
    const unsigned short* __restrict__ Qp = Qb + ((size_t)b * SEQ + qrow0) * HD;

    short8 qf0 = *(const short8*)(Qp + lr * HD +      lg * 8);
    short8 qf1 = *(const short8*)(Qp + lr * HD + 32 + lg * 8);

    f32x4 o[4];
    #pragma unroll
    for (int nt = 0; nt < 4; ++nt) o[nt] = f32x4{0.f, 0.f, 0.f, 0.f};
    float lrun = 0.f;

    const int c0 = slice * (qb + 1);
    const int c1 = c0 + (qb + 1);
    const int swz = (lr & 7) << 3;

    for (int it = c0; it < c1; ++it) {
        const int kvb = it * 64;
        // ---- cooperative stage: wave w copies its 1KB share of K and V
        {
            const unsigned short* gk = Kp + (size_t)kvb * HD + w * 512 + lane * 8;
            const unsigned short* gv = Vp + (size_t)it * 4096 + w * 512 + lane * 8;
            __builtin_amdgcn_global_load_lds(
                (const __attribute__((address_space(1))) void*)gk,
                (__attribute__((address_space(3))) void*)(ldsK + w * 512), 16, 0, 0);
            __builtin_amdgcn_global_load_lds(
                (const __attribute__((address_space(1))) void*)gv,
                (__attribute__((address_space(3))) void*)(ldsV + w * 512), 16, 0, 0);
        }
        __syncthreads();   // drains vmcnt -> tiles resident for all waves

        if (kvb <= qwmax) {
            // ---- QK^T (swapped): A = K rows from LDS, B = Q regs
            f32x4 s0 = f32x4{0.f, 0.f, 0.f, 0.f};
            f32x4 s1 = f32x4{0.f, 0.f, 0.f, 0.f};
            f32x4 s2 = f32x4{0.f, 0.f, 0.f, 0.f};
            f32x4 s3 = f32x4{0.f, 0.f, 0.f, 0.f};
            {
                short8 ka0 = *(const short8*)&ldsK[(0 * 16 + lr) * 64 + ((lg * 8)      ^ swz)];
                short8 kb0 = *(const short8*)&ldsK[(0 * 16 + lr) * 64 + ((lg * 8 + 32) ^ swz)];
                short8 ka1 = *(const short8*)&ldsK[(1 * 16 + lr) * 64 + ((lg * 8)      ^ swz)];
                short8 kb1 = *(const short8*)&ldsK[(1 * 16 + lr) * 64 + ((lg * 8 + 32) ^ swz)];
                short8 ka2 = *(const short8*)&ldsK[(2 * 16 + lr) * 64 + ((lg * 8)      ^ swz)];
                short8 kb2 = *(const short8*)&ldsK[(2 * 16 + lr) * 64 + ((lg * 8 + 32) ^ swz)];
                short8 ka3 = *(const short8*)&ldsK[(3 * 16 + lr) * 64 + ((lg * 8)      ^ swz)];
                short8 kb3 = *(const short8*)&ldsK[(3 * 16 + lr) * 64 + ((lg * 8 + 32) ^ swz)];
                s0 = __builtin_amdgcn_mfma_f32_16x16x32_bf16(ka0, qf0, s0, 0, 0, 0);
                s0 = __builtin_amdgcn_mfma_f32_16x16x32_bf16(kb0, qf1, s0, 0, 0, 0);
                s1 = __builtin_amdgcn_mfma_f32_16x16x32_bf16(ka1, qf0, s1, 0, 0, 0);
                s1 = __builtin_amdgcn_mfma_f32_16x16x32_bf16(kb1, qf1, s1, 0, 0, 0);
                s2 = __builtin_amdgcn_mfma_f32_16x16x32_bf16(ka2, qf0, s2, 0, 0, 0);
                s2 = __builtin_amdgcn_mfma_f32_16x16x32_bf16(kb2, qf1, s2, 0, 0, 0);
                s3 = __builtin_amdgcn_mfma_f32_16x16x32_bf16(ka3, qf0, s3, 0, 0, 0);
                s3 = __builtin_amdgcn_mfma_f32_16x16x32_bf16(kb3, qf1, s3, 0, 0, 0);
            }

            if (kvb + 63 > qrow0) {          // FIX: mask if chunk passes FIRST row
                const int qg = qrow0 + lr;
                #pragma unroll
                for (int r = 0; r < 4; ++r) {
                    int ky = kvb + lg * 4 + r;
                    if (ky      > qg) s0[r] = -1e30f;
                    if (ky + 16 > qg) s1[r] = -1e30f;
                    if (ky + 32 > qg) s2[r] = -1e30f;
                    if (ky + 48 > qg) s3[r] = -1e30f;
                }
            }

            // ---- p = exp2(s) (fixed m=0), per-lane l accumulation
            float p0[4], p1[4], p2[4], p3[4];
            #pragma unroll
            for (int r = 0; r < 4; ++r) {
                p0[r] = exp2f(s0[r]);
                p1[r] = exp2f(s1[r]);
                p2[r] = exp2f(s2[r]);
                p3[r] = exp2f(s3[r]);
            }
            lrun += ((p0[0] + p0[1]) + (p0[2] + p0[3])) + ((p1[0] + p1[1]) + (p1[2] + p1[3]))
                  + ((p2[0] + p2[1]) + (p2[2] + p2[3])) + ((p3[0] + p3[1]) + (p3[2] + p3[3]));

            uint4v ua, ub;
            asm("v_cvt_pk_bf16_f32 %0, %1, %2" : "=v"(ua[0]) : "v"(p0[0]), "v"(p0[1]));
            asm("v_cvt_pk_bf16_f32 %0, %1, %2" : "=v"(ua[1]) : "v"(p0[2]), "v"(p0[3]));
            asm("v_cvt_pk_bf16_f32 %0, %1, %2" : "=v"(ua[2]) : "v"(p1[0]), "v"(p1[1]));
            asm("v_cvt_pk_bf16_f32 %0, %1, %2" : "=v"(ua[3]) : "v"(p1[2]), "v"(p1[3]));
            asm("v_cvt_pk_bf16_f32 %0, %1, %2" : "=v"(ub[0]) : "v"(p2[0]), "v"(p2[1]));
            asm("v_cvt_pk_bf16_f32 %0, %1, %2" : "=v"(ub[1]) : "v"(p2[2]), "v"(p2[3]));
            asm("v_cvt_pk_bf16_f32 %0, %1, %2" : "=v"(ub[2]) : "v"(p3[0]), "v"(p3[1]));
            asm("v_cvt_pk_bf16_f32 %0, %1, %2" : "=v"(ub[3]) : "v"(p3[2]), "v"(p3[3]));
            short8 pba = *(short8*)&ua;      // keys kvb..kvb+31
            short8 pbb = *(short8*)&ub;      // keys kvb+32..kvb+63

            // ---- PV: A = V rows from LDS, B = P regs
            short8 va0 = *(const short8*)&ldsV[(0 * 16 + lr) * 64 + ((lg * 8)      ^ swz)];
            short8 vb0 = *(const short8*)&ldsV[(0 * 16 + lr) * 64 + ((lg * 8 + 32) ^ swz)];
            short8 va1 = *(const short8*)&ldsV[(1 * 16 + lr) * 64 + ((lg * 8)      ^ swz)];
            short8 vb1 = *(const short8*)&ldsV[(1 * 16 + lr) * 64 + ((lg * 8 + 32) ^ swz)];
            short8 va2 = *(const short8*)&ldsV[(2 * 16 + lr) * 64 + ((lg * 8)      ^ swz)];
            short8 vb2 = *(const short8*)&ldsV[(2 * 16 + lr) * 64 + ((lg * 8 + 32) ^ swz)];
            short8 va3 = *(const short8*)&ldsV[(3 * 16 + lr) * 64 + ((lg * 8)      ^ swz)];
            short8 vb3 = *(const short8*)&ldsV[(3 * 16 + lr) * 64 + ((lg * 8 + 32) ^ swz)];
            o[0] = __builtin_amdgcn_mfma_f32_16x16x32_bf16(va0, pba, o[0], 0, 0, 0);
            o[1] = __builtin_amdgcn_mfma_f32_16x16x32_bf16(va1, pba, o[1], 0, 0, 0);
            o[2] = __builtin_amdgcn_mfma_f32_16x16x32_bf16(va2, pba, o[2], 0, 0, 0);
            o[3] = __builtin_amdgcn_mfma_f32_16x16x32_bf16(va3, pba, o[3], 0, 0, 0);
            o[0] = __builtin_amdgcn_mfma_f32_16x16x32_bf16(vb0, pbb, o[0], 0, 0, 0);
            o[1] = __builtin_amdgcn_mfma_f32_16x16x32_bf16(vb1, pbb, o[1], 0, 0, 0);
            o[2] = __builtin_amdgcn_mfma_f32_16x16x32_bf16(vb2, pbb, o[2], 0, 0, 0);
            o[3] = __builtin_amdgcn_mfma_f32_16x16x32_bf16(vb3, pbb, o[3], 0, 0, 0);
        }
        __syncthreads();   // all waves done reading before next chunk overwrites
    }

    // ---- per-q l across lane groups (exact: all terms share m=0)
    lrun += __shfl_xor(lrun, 16);
    lrun += __shfl_xor(lrun, 32);

    // ---- write slice partials: o[nt][r] = O[q=lr][d = nt*16+lg*4+r]
    const size_t prow = (((size_t)slice * 4 + b) * 32 + qb) * 128 + w * 16 + lr;
    float* po = part_o + prow * 64;
    #pragma unroll
    for (int nt = 0; nt < 4; ++nt)
        *(f32x4*)(po + nt * 16 + lg * 4) = o[nt];
    if (lg == 0) part_l[prow] = lrun;
}

// ---------------------------------------------------------------------------
// Merge: out = (o_s0 + o_s1) / (l_s0 + l_s1).
// ---------------------------------------------------------------------------
__global__ __launch_bounds__(256) void merge_kernel(
        const float* __restrict__ part_o, const float* __restrict__ part_l,
        float* __restrict__ out) {
    int idx = blockIdx.x * 256 + threadIdx.x;    // 0..262143
    int d4  = (idx & 15) * 4;
    int row = idx >> 4;                           // 0..16383 == b*4096 + q
    f32x4 a0 = *(const f32x4*)(part_o + (size_t)row * 64 + d4);
    f32x4 a1 = *(const f32x4*)(part_o + 1048576 + (size_t)row * 64 + d4);
    float L  = part_l[row] + part_l[16384 + row];
    float inv = 1.0f / L;
    f32x4 r;
    r[0] = (a0[0] + a1[0]) * inv;
    r[1] = (a0[1] + a1[1]) * inv;
    r[2] = (a0[2] + a1[2]) * inv;
    r[3] = (a0[3] + a1[3]) * inv;
    *(f32x4*)(out + (size_t)row * 64 + d4) = r;
}

// ---------------------------------------------------------------------------
extern "C" void kernel_launch(void* const* d_in, const int* in_sizes, int n_in,
                              void* d_out, int out_size, void* d_ws, size_t ws_size,
                              hipStream_t stream) {
    const float* H  = (const float*)d_in[0];
    const float* Wq = (const float*)d_in[1];
    const float* Wk = (const float*)d_in[2];
    const float* Wv = (const float*)d_in[3];
    float* out = (float*)d_out;

    // ws (bf16): Qb[1M] | Kb[1M] | Vt[1M] | Wt[196608]  then (f32): part_o[2M] | part_l[32K]
    unsigned short* Qb = (unsigned short*)d_ws;
    unsigned short* Kb = Qb + (size_t)NB * SEQ * HD;
    unsigned short* Vt = Kb + (size_t)NB * SEQ * HD;
    unsigned short* Wt = Vt + (size_t)NB * SEQ * HD;
    float* part_o = (float*)(Wt + 3 * 65536);     // 2*4*32*128*64 = 2,097,152 f32 (8 MB)
    float* part_l = part_o + 2097152;             // 2*16384 f32 (128 KB); total ws ~14.6 MB

    wprep_kernel<<<768, 256, 0, stream>>>(Wq, Wk, Wv, Wt);
    qkv_kernel<<<NB * SEQ / 32, 256, 0, stream>>>(H, Wt, Qb, Kb, Vt);
    attn_kernel<<<256, 512, 0, stream>>>(Qb, Kb, Vt, part_o, part_l);
    merge_kernel<<<1024, 256, 0, stream>>>(part_o, part_l, out);
}

// Round 16
// 70.086 us; speedup vs baseline: 3.7601x; 1.2647x over previous
//
#include <hip/hip_runtime.h>
#include <hip/hip_bf16.h>
#include <stdint.h>

#define SEQ 4096
#define EMB 1024
#define HD  64
#define NB  4

typedef __attribute__((ext_vector_type(8))) short short8;   // 8 x bf16 (4 VGPRs)
typedef __attribute__((ext_vector_type(4))) float f32x4;
typedef __attribute__((ext_vector_type(4))) unsigned int uint4v;

// RNE float -> bf16 bits (no NaN inputs here)
static __device__ __forceinline__ unsigned short f2bf(float f) {
    unsigned int u = __float_as_uint(f);
    u += 0x7fffu + ((u >> 16) & 1u);
    return (unsigned short)(u >> 16);
}

// ---------------------------------------------------------------------------
// Prep: Wt[m][d][e] = bf16(W_m[e][d]),  m in {q,k,v}.  3*64*1024 elements.
// Wq is pre-scaled by log2(e)/sqrt(64) so attn needs no scale multiply.
// ---------------------------------------------------------------------------
__global__ __launch_bounds__(256) void wprep_kernel(
        const float* __restrict__ Wq, const float* __restrict__ Wk,
        const float* __restrict__ Wv, unsigned short* __restrict__ Wt) {
    int idx = blockIdx.x * 256 + threadIdx.x;       // < 3*65536
    int m = idx >> 16;
    int r = idx & 65535;
    int d = r >> 10;
    int e = r & 1023;
    const float* W = (m == 0) ? Wq : (m == 1) ? Wk : Wv;
    float v = W[e * HD + d];
    if (m == 0) v *= 0.18033688011111793f;          // log2(e)/sqrt(64)
    Wt[idx] = f2bf(v);
}

// ---------------------------------------------------------------------------
// QKV v2 — LDS-cooperative (same medicine as attn, R12-ablation-driven).
// grid = 256 blocks x 64 rows x 512 thr (8 waves = 4 rowtiles x 2 colhalves).
// Wave owns 16 rows x 96 cols exclusively -> NO cross-wave reduction.
// K-loop: 16 chunks of 64; per chunk stage Wt-chunk (24KB: 192 rows x 128B)
// and H-chunk (16KB: 64 rows x 256B) via global_load_lds(16B) with
// PRE-SWIZZLED per-lane source (16B-block ^= row&7; linear LDS dest — m173).
// 2-phase double buffer: stage chunk c+1 into buf^1, compute chunk c, 1
// barrier/chunk. Fragments from LDS: conflict-free (block XOR swizzle).
// Epilogue: acc -> LDS (stride 200 f32, conflict-free) -> coalesced stores;
// K stored column-XOR-swizzled (d0 ^ ((row&7)<<3)); V chunked
// Vt[b][s>>6][d][64] with col e = ((t&32)|sigma(t&31)) ^ ((d&7)<<3)
// (matches attn's reads exactly — layouts unchanged from R15).
// ---------------------------------------------------------------------------
__global__ __launch_bounds__(512, 4) void qkv_kernel(
        const float* __restrict__ H, const unsigned short* __restrict__ Wt,
        unsigned short* __restrict__ Qb, unsigned short* __restrict__ Kb,
        unsigned short* __restrict__ Vt) {
    __shared__ unsigned char smem[81920];            // 80 KB
    unsigned short* ldsW = (unsigned short*)smem;    // [2][192][64] bf16 (2x24KB)
    float* ldsH = (float*)(smem + 49152);            // [2][64][64] f32  (2x16KB)
    float* ldsO = (float*)smem;                      // epilogue overlay [64][200] f32

    const int tid  = threadIdx.x;
    const int w    = tid >> 6;
    const int lane = tid & 63;
    const int lr = lane & 15, lg = lane >> 4;
    const int rt = w >> 1, ch = w & 1;
    const int rowbase = blockIdx.x * 64;

    f32x4 acc[6];
    #pragma unroll
    for (int nt = 0; nt < 6; ++nt) acc[nt] = f32x4{0.f, 0.f, 0.f, 0.f};

    auto stage = [&](int buf, int c) {
        const int kk0 = c * 64;
        // Wt chunk: 24 wave-insts total, wave w issues 3
        #pragma unroll
        for (int ii = 0; ii < 3; ++ii) {
            int i = w * 3 + ii;
            int rowidx = 8 * i + (lane >> 3);            // 0..191  (m*64+d)
            int sb = (lane & 7) ^ (lane >> 3);           // src 16B-block ^ (row&7)
            const unsigned short* src = Wt + rowidx * EMB + kk0 + sb * 8;
            __builtin_amdgcn_global_load_lds(
                (const __attribute__((address_space(1))) void*)src,
                (__attribute__((address_space(3))) void*)(ldsW + buf * 12288 + i * 512 + lane * 8),
                16, 0, 0);
        }
        // H chunk: 16 wave-insts total, wave w issues 2
        #pragma unroll
        for (int ii = 0; ii < 2; ++ii) {
            int i = w * 2 + ii;
            int rowidx = 4 * i + (lane >> 4);            // 0..63
            int key = rowidx & 7;
            int sb = (lane & 15) ^ key;                  // src 16B-block ^ (row&7)
            const float* src = H + (size_t)(rowbase + rowidx) * EMB + kk0 + sb * 4;
            __builtin_amdgcn_global_load_lds(
                (const __attribute__((address_space(1))) void*)src,
                (__attribute__((address_space(3))) void*)(ldsH + buf * 4096 + i * 256 + lane * 4),
                16, 0, 0);
        }
    };

    auto compute = [&](int buf) {
        const int hrow = rt * 16 + lr;
        const int hkey = lr & 7;
        #pragma unroll
        for (int ks = 0; ks < 2; ++ks) {
            int b0 = ks * 8 + lg * 2;
            f32x4 h0 = *(const f32x4*)(ldsH + buf * 4096 + hrow * 64 + ((b0 ^ hkey) * 4));
            f32x4 h1 = *(const f32x4*)(ldsH + buf * 4096 + hrow * 64 + (((b0 + 1) ^ hkey) * 4));
            uint4v ua;
            asm("v_cvt_pk_bf16_f32 %0, %1, %2" : "=v"(ua[0]) : "v"(h0[0]), "v"(h0[1]));
            asm("v_cvt_pk_bf16_f32 %0, %1, %2" : "=v"(ua[1]) : "v"(h0[2]), "v"(h0[3]));
            asm("v_cvt_pk_bf16_f32 %0, %1, %2" : "=v"(ua[2]) : "v"(h1[0]), "v"(h1[1]));
            asm("v_cvt_pk_bf16_f32 %0, %1, %2" : "=v"(ua[3]) : "v"(h1[2]), "v"(h1[3]));
            short8 af = *(short8*)&ua;
            #pragma unroll
            for (int nt = 0; nt < 6; ++nt) {
                int f = ch * 6 + nt;
                int row = f * 16 + lr;                   // (row&7) == lr&7 == hkey
                int blk = (ks * 4 + lg) ^ hkey;
                short8 bf_ = *(const short8*)(ldsW + buf * 12288 + row * 64 + blk * 8);
                acc[nt] = __builtin_amdgcn_mfma_f32_16x16x32_bf16(af, bf_, acc[nt], 0, 0, 0);
            }
        }
    };

    stage(0, 0);
    __syncthreads();
    for (int c = 0; c < 16; ++c) {
        if (c < 15) stage((c + 1) & 1, c + 1);
        compute(c & 1);
        __syncthreads();
    }

    // ---- epilogue: acc -> ldsO [64][200] (conflict-free), then coalesced out
    #pragma unroll
    for (int nt = 0; nt < 6; ++nt)
        #pragma unroll
        for (int r = 0; r < 4; ++r)
            ldsO[(rt * 16 + lg * 4 + r) * 200 + ch * 96 + nt * 16 + lr] = acc[nt][r];
    __syncthreads();

    {   // Q and K: 512 threads, row = tid>>3 (0..63), 8 cols each
        const int row = tid >> 3;
        const int d0  = (tid & 7) * 8;
        const size_t grow = (size_t)(rowbase + row);
        short8 uq, uk;
        #pragma unroll
        for (int j = 0; j < 8; ++j) {
            uq[j] = (short)f2bf(ldsO[row * 200 + d0 + j]);
            uk[j] = (short)f2bf(ldsO[row * 200 + 64 + d0 + j]);
        }
        *(short8*)(Qb + grow * HD + d0) = uq;
        *(short8*)(Kb + grow * HD + (d0 ^ ((row & 7) << 3))) = uk;
    }
    {   // V: block covers exactly one 64-chunk; d = tid>>3, 4 u32 pairs each
        const int d  = tid >> 3;
        const int j  = tid & 7;
        const int b  = rowbase >> 12;
        const int ci = (rowbase & (SEQ - 1)) >> 6;
        unsigned short* vrow = Vt + (((size_t)b * 64 + ci) * 64 + d) * 64;
        const int dsw = (d & 7) << 3;
        #pragma unroll
        for (int k4 = 0; k4 < 4; ++k4) {
            int t0 = j * 2 + k4 * 16;            // even t in 0..62
            int tt = t0 & 31;
            int p0 = ((tt & 12) << 1) | (tt & 3) | ((tt & 16) >> 2);
            int e  = ((t0 & 32) | p0) ^ dsw;
            unsigned int val = (unsigned int)f2bf(ldsO[t0 * 200 + 128 + d])
                             | ((unsigned int)f2bf(ldsO[(t0 + 1) * 200 + 128 + d]) << 16);
            *(unsigned int*)(vrow + e) = val;
        }
    }
}

// ---------------------------------------------------------------------------
// Flash attention, LDS-COOPERATIVE (unchanged from R15 — passed at ~40us).
// ---------------------------------------------------------------------------
__global__ __launch_bounds__(512, 2) void attn_kernel(
        const unsigned short* __restrict__ Qb, const unsigned short* __restrict__ Kb,
        const unsigned short* __restrict__ Vt,
        float* __restrict__ part_o, float* __restrict__ part_l) {
    __shared__ unsigned short ldsK[64 * 64];   // 8 KB (swizzled image)
    __shared__ unsigned short ldsV[64 * 64];   // 8 KB (swizzled image)
    const int tid  = threadIdx.x;
    const int w    = tid >> 6;
    const int lane = tid & 63;
    const int lr = lane & 15, lg = lane >> 4;

    const int bid   = blockIdx.x;
    const int b     = bid & 3;
    const int qb    = (bid >> 2) & 31;
    const int slice = bid >> 7;                // 0 or 1
    const int qrow0 = qb * 128 + w * 16;       // this wave's 16 q-rows
    const int qwmax = qrow0 + 15;

    const unsigned short* __restrict__ Kp = Kb + (size_t)b * SEQ * HD;
    const unsigned short* __restrict__ Vp = Vt + (size_t)b * 64 * 4096;
    const unsigned short* __restrict__ Qp = Qb + ((size_t)b * SEQ + qrow0) * HD;

    short8 qf0 = *(const short8*)(Qp + lr * HD +      lg * 8);
    short8 qf1 = *(const short8*)(Qp + lr * HD + 32 + lg * 8);

    f32x4 o[4];
    #pragma unroll
    for (int nt = 0; nt < 4; ++nt) o[nt] = f32x4{0.f, 0.f, 0.f, 0.f};
    float lrun = 0.f;

    const int c0 = slice * (qb + 1);
    const int c1 = c0 + (qb + 1);
    const int swz = (lr & 7) << 3;

    for (int it = c0; it < c1; ++it) {
        const int kvb = it * 64;
        {
            const unsigned short* gk = Kp + (size_t)kvb * HD + w * 512 + lane * 8;
            const unsigned short* gv = Vp + (size_t)it * 4096 + w * 512 + lane * 8;
            __builtin_amdgcn_global_load_lds(
                (const __attribute__((address_space(1))) void*)gk,
                (__attribute__((address_space(3))) void*)(ldsK + w * 512), 16, 0, 0);
            __builtin_amdgcn_global_load_lds(
                (const __attribute__((address_space(1))) void*)gv,
                (__attribute__((address_space(3))) void*)(ldsV + w * 512), 16, 0, 0);
        }
        __syncthreads();

        if (kvb <= qwmax) {
            f32x4 s0 = f32x4{0.f, 0.f, 0.f, 0.f};
            f32x4 s1 = f32x4{0.f, 0.f, 0.f, 0.f};
            f32x4 s2 = f32x4{0.f, 0.f, 0.f, 0.f};
            f32x4 s3 = f32x4{0.f, 0.f, 0.f, 0.f};
            {
                short8 ka0 = *(const short8*)&ldsK[(0 * 16 + lr) * 64 + ((lg * 8)      ^ swz)];
                short8 kb0 = *(const short8*)&ldsK[(0 * 16 + lr) * 64 + ((lg * 8 + 32) ^ swz)];
                short8 ka1 = *(const short8*)&ldsK[(1 * 16 + lr) * 64 + ((lg * 8)      ^ swz)];
                short8 kb1 = *(const short8*)&ldsK[(1 * 16 + lr) * 64 + ((lg * 8 + 32) ^ swz)];
                short8 ka2 = *(const short8*)&ldsK[(2 * 16 + lr) * 64 + ((lg * 8)      ^ swz)];
                short8 kb2 = *(const short8*)&ldsK[(2 * 16 + lr) * 64 + ((lg * 8 + 32) ^ swz)];
                short8 ka3 = *(const short8*)&ldsK[(3 * 16 + lr) * 64 + ((lg * 8)      ^ swz)];
                short8 kb3 = *(const short8*)&ldsK[(3 * 16 + lr) * 64 + ((lg * 8 + 32) ^ swz)];
                s0 = __builtin_amdgcn_mfma_f32_16x16x32_bf16(ka0, qf0, s0, 0, 0, 0);
                s0 = __builtin_amdgcn_mfma_f32_16x16x32_bf16(kb0, qf1, s0, 0, 0, 0);
                s1 = __builtin_amdgcn_mfma_f32_16x16x32_bf16(ka1, qf0, s1, 0, 0, 0);
                s1 = __builtin_amdgcn_mfma_f32_16x16x32_bf16(kb1, qf1, s1, 0, 0, 0);
                s2 = __builtin_amdgcn_mfma_f32_16x16x32_bf16(ka2, qf0, s2, 0, 0, 0);
                s2 = __builtin_amdgcn_mfma_f32_16x16x32_bf16(kb2, qf1, s2, 0, 0, 0);
                s3 = __builtin_amdgcn_mfma_f32_16x16x32_bf16(ka3, qf0, s3, 0, 0, 0);
                s3 = __builtin_amdgcn_mfma_f32_16x16x32_bf16(kb3, qf1, s3, 0, 0, 0);
            }

            if (kvb + 63 > qrow0) {          // mask if chunk passes FIRST row
                const int qg = qrow0 + lr;
                #pragma unroll
                for (int r = 0; r < 4; ++r) {
                    int ky = kvb + lg * 4 + r;
                    if (ky      > qg) s0[r] = -1e30f;
                    if (ky + 16 > qg) s1[r] = -1e30f;
                    if (ky + 32 > qg) s2[r] = -1e30f;
                    if (ky + 48 > qg) s3[r] = -1e30f;
                }
            }

            float p0[4], p1[4], p2[4], p3[4];
            #pragma unroll
            for (int r = 0; r < 4; ++r) {
                p0[r] = exp2f(s0[r]);
                p1[r] = exp2f(s1[r]);
                p2[r] = exp2f(s2[r]);
                p3[r] = exp2f(s3[r]);
            }
            lrun += ((p0[0] + p0[1]) + (p0[2] + p0[3])) + ((p1[0] + p1[1]) + (p1[2] + p1[3]))
                  + ((p2[0] + p2[1]) + (p2[2] + p2[3])) + ((p3[0] + p3[1]) + (p3[2] + p3[3]));

            uint4v ua, ub;
            asm("v_cvt_pk_bf16_f32 %0, %1, %2" : "=v"(ua[0]) : "v"(p0[0]), "v"(p0[1]));
            asm("v_cvt_pk_bf16_f32 %0, %1, %2" : "=v"(ua[1]) : "v"(p0[2]), "v"(p0[3]));
            asm("v_cvt_pk_bf16_f32 %0, %1, %2" : "=v"(ua[2]) : "v"(p1[0]), "v"(p1[1]));
            asm("v_cvt_pk_bf16_f32 %0, %1, %2" : "=v"(ua[3]) : "v"(p1[2]), "v"(p1[3]));
            asm("v_cvt_pk_bf16_f32 %0, %1, %2" : "=v"(ub[0]) : "v"(p2[0]), "v"(p2[1]));
            asm("v_cvt_pk_bf16_f32 %0, %1, %2" : "=v"(ub[1]) : "v"(p2[2]), "v"(p2[3]));
            asm("v_cvt_pk_bf16_f32 %0, %1, %2" : "=v"(ub[2]) : "v"(p3[0]), "v"(p3[1]));
            asm("v_cvt_pk_bf16_f32 %0, %1, %2" : "=v"(ub[3]) : "v"(p3[2]), "v"(p3[3]));
            short8 pba = *(short8*)&ua;      // keys kvb..kvb+31
            short8 pbb = *(short8*)&ub;      // keys kvb+32..kvb+63

            short8 va0 = *(const short8*)&ldsV[(0 * 16 + lr) * 64 + ((lg * 8)      ^ swz)];
            short8 vb0 = *(const short8*)&ldsV[(0 * 16 + lr) * 64 + ((lg * 8 + 32) ^ swz)];
            short8 va1 = *(const short8*)&ldsV[(1 * 16 + lr) * 64 + ((lg * 8)      ^ swz)];
            short8 vb1 = *(const short8*)&ldsV[(1 * 16 + lr) * 64 + ((lg * 8 + 32) ^ swz)];
            short8 va2 = *(const short8*)&ldsV[(2 * 16 + lr) * 64 + ((lg * 8)      ^ swz)];
            short8 vb2 = *(const short8*)&ldsV[(2 * 16 + lr) * 64 + ((lg * 8 + 32) ^ swz)];
            short8 va3 = *(const short8*)&ldsV[(3 * 16 + lr) * 64 + ((lg * 8)      ^ swz)];
            short8 vb3 = *(const short8*)&ldsV[(3 * 16 + lr) * 64 + ((lg * 8 + 32) ^ swz)];
            o[0] = __builtin_amdgcn_mfma_f32_16x16x32_bf16(va0, pba, o[0], 0, 0, 0);
            o[1] = __builtin_amdgcn_mfma_f32_16x16x32_bf16(va1, pba, o[1], 0, 0, 0);
            o[2] = __builtin_amdgcn_mfma_f32_16x16x32_bf16(va2, pba, o[2], 0, 0, 0);
            o[3] = __builtin_amdgcn_mfma_f32_16x16x32_bf16(va3, pba, o[3], 0, 0, 0);
            o[0] = __builtin_amdgcn_mfma_f32_16x16x32_bf16(vb0, pbb, o[0], 0, 0, 0);
            o[1] = __builtin_amdgcn_mfma_f32_16x16x32_bf16(vb1, pbb, o[1], 0, 0, 0);
            o[2] = __builtin_amdgcn_mfma_f32_16x16x32_bf16(vb2, pbb, o[2], 0, 0, 0);
            o[3] = __builtin_amdgcn_mfma_f32_16x16x32_bf16(vb3, pbb, o[3], 0, 0, 0);
        }
        __syncthreads();
    }

    lrun += __shfl_xor(lrun, 16);
    lrun += __shfl_xor(lrun, 32);

    const size_t prow = (((size_t)slice * 4 + b) * 32 + qb) * 128 + w * 16 + lr;
    float* po = part_o + prow * 64;
    #pragma unroll
    for (int nt = 0; nt < 4; ++nt)
        *(f32x4*)(po + nt * 16 + lg * 4) = o[nt];
    if (lg == 0) part_l[prow] = lrun;
}

// ---------------------------------------------------------------------------
// Merge: out = (o_s0 + o_s1) / (l_s0 + l_s1).
// ---------------------------------------------------------------------------
__global__ __launch_bounds__(256) void merge_kernel(
        const float* __restrict__ part_o, const float* __restrict__ part_l,
        float* __restrict__ out) {
    int idx = blockIdx.x * 256 + threadIdx.x;    // 0..262143
    int d4  = (idx & 15) * 4;
    int row = idx >> 4;                           // 0..16383 == b*4096 + q
    f32x4 a0 = *(const f32x4*)(part_o + (size_t)row * 64 + d4);
    f32x4 a1 = *(const f32x4*)(part_o + 1048576 + (size_t)row * 64 + d4);
    float L  = part_l[row] + part_l[16384 + row];
    float inv = 1.0f / L;
    f32x4 r;
    r[0] = (a0[0] + a1[0]) * inv;
    r[1] = (a0[1] + a1[1]) * inv;
    r[2] = (a0[2] + a1[2]) * inv;
    r[3] = (a0[3] + a1[3]) * inv;
    *(f32x4*)(out + (size_t)row * 64 + d4) = r;
}

// ---------------------------------------------------------------------------
extern "C" void kernel_launch(void* const* d_in, const int* in_sizes, int n_in,
                              void* d_out, int out_size, void* d_ws, size_t ws_size,
                              hipStream_t stream) {
    const float* H  = (const float*)d_in[0];
    const float* Wq = (const float*)d_in[1];
    const float* Wk = (const float*)d_in[2];
    const float* Wv = (const float*)d_in[3];
    float* out = (float*)d_out;

    // ws (bf16): Qb[1M] | Kb[1M] | Vt[1M] | Wt[196608]  then (f32): part_o[2M] | part_l[32K]
    unsigned short* Qb = (unsigned short*)d_ws;
    unsigned short* Kb = Qb + (size_t)NB * SEQ * HD;
    unsigned short* Vt = Kb + (size_t)NB * SEQ * HD;
    unsigned short* Wt = Vt + (size_t)NB * SEQ * HD;
    float* part_o = (float*)(Wt + 3 * 65536);     // 2*4*32*128*64 = 2,097,152 f32 (8 MB)
    float* part_l = part_o + 2097152;             // 2*16384 f32 (128 KB)

    wprep_kernel<<<768, 256, 0, stream>>>(Wq, Wk, Wv, Wt);
    qkv_kernel<<<NB * SEQ / 64, 512, 0, stream>>>(H, Wt, Qb, Kb, Vt);
    attn_kernel<<<256, 512, 0, stream>>>(Qb, Kb, Vt, part_o, part_l);
    merge_kernel<<<1024, 256, 0, stream>>>(part_o, part_l, out);
}

// Round 17
// 54.983 us; speedup vs baseline: 4.7930x; 1.2747x over previous
//
#include <hip/hip_runtime.h>
#include <hip/hip_bf16.h>
#include <stdint.h>

#define SEQ 4096
#define EMB 1024
#define HD  64
#define NB  4

typedef __attribute__((ext_vector_type(8))) short short8;   // 8 x bf16 (4 VGPRs)
typedef __attribute__((ext_vector_type(4))) float f32x4;
typedef __attribute__((ext_vector_type(4))) unsigned int uint4v;

// RNE float -> bf16 bits (no NaN inputs here)
static __device__ __forceinline__ unsigned short f2bf(float f) {
    unsigned int u = __float_as_uint(f);
    u += 0x7fffu + ((u >> 16) & 1u);
    return (unsigned short)(u >> 16);
}

// ---------------------------------------------------------------------------
// Prep: Wt[m][d][e] = bf16(W_m[e][d]),  m in {q,k,v}.  3*64*1024 elements.
// Wq is pre-scaled by log2(e)/sqrt(64) so attn needs no scale multiply.
// ---------------------------------------------------------------------------
__global__ __launch_bounds__(256) void wprep_kernel(
        const float* __restrict__ Wq, const float* __restrict__ Wk,
        const float* __restrict__ Wv, unsigned short* __restrict__ Wt) {
    int idx = blockIdx.x * 256 + threadIdx.x;       // < 3*65536
    int m = idx >> 16;
    int r = idx & 65535;
    int d = r >> 10;
    int e = r & 1023;
    const float* W = (m == 0) ? Wq : (m == 1) ? Wk : Wv;
    float v = W[e * HD + d];
    if (m == 0) v *= 0.18033688011111793f;          // log2(e)/sqrt(64)
    Wt[idx] = f2bf(v);
}

// ---------------------------------------------------------------------------
// QKV v2 — LDS-cooperative (unchanged from R16: ~22us).
// ---------------------------------------------------------------------------
__global__ __launch_bounds__(512, 4) void qkv_kernel(
        const float* __restrict__ H, const unsigned short* __restrict__ Wt,
        unsigned short* __restrict__ Qb, unsigned short* __restrict__ Kb,
        unsigned short* __restrict__ Vt) {
    __shared__ unsigned char smem[81920];            // 80 KB
    unsigned short* ldsW = (unsigned short*)smem;    // [2][192][64] bf16 (2x24KB)
    float* ldsH = (float*)(smem + 49152);            // [2][64][64] f32  (2x16KB)
    float* ldsO = (float*)smem;                      // epilogue overlay [64][200] f32

    const int tid  = threadIdx.x;
    const int w    = tid >> 6;
    const int lane = tid & 63;
    const int lr = lane & 15, lg = lane >> 4;
    const int rt = w >> 1, ch = w & 1;
    const int rowbase = blockIdx.x * 64;

    f32x4 acc[6];
    #pragma unroll
    for (int nt = 0; nt < 6; ++nt) acc[nt] = f32x4{0.f, 0.f, 0.f, 0.f};

    auto stage = [&](int buf, int c) {
        const int kk0 = c * 64;
        #pragma unroll
        for (int ii = 0; ii < 3; ++ii) {
            int i = w * 3 + ii;
            int rowidx = 8 * i + (lane >> 3);            // 0..191  (m*64+d)
            int sb = (lane & 7) ^ (lane >> 3);           // src 16B-block ^ (row&7)
            const unsigned short* src = Wt + rowidx * EMB + kk0 + sb * 8;
            __builtin_amdgcn_global_load_lds(
                (const __attribute__((address_space(1))) void*)src,
                (__attribute__((address_space(3))) void*)(ldsW + buf * 12288 + i * 512 + lane * 8),
                16, 0, 0);
        }
        #pragma unroll
        for (int ii = 0; ii < 2; ++ii) {
            int i = w * 2 + ii;
            int rowidx = 4 * i + (lane >> 4);            // 0..63
            int key = rowidx & 7;
            int sb = (lane & 15) ^ key;                  // src 16B-block ^ (row&7)
            const float* src = H + (size_t)(rowbase + rowidx) * EMB + kk0 + sb * 4;
            __builtin_amdgcn_global_load_lds(
                (const __attribute__((address_space(1))) void*)src,
                (__attribute__((address_space(3))) void*)(ldsH + buf * 4096 + i * 256 + lane * 4),
                16, 0, 0);
        }
    };

    auto compute = [&](int buf) {
        const int hrow = rt * 16 + lr;
        const int hkey = lr & 7;
        #pragma unroll
        for (int ks = 0; ks < 2; ++ks) {
            int b0 = ks * 8 + lg * 2;
            f32x4 h0 = *(const f32x4*)(ldsH + buf * 4096 + hrow * 64 + ((b0 ^ hkey) * 4));
            f32x4 h1 = *(const f32x4*)(ldsH + buf * 4096 + hrow * 64 + (((b0 + 1) ^ hkey) * 4));
            uint4v ua;
            asm("v_cvt_pk_bf16_f32 %0, %1, %2" : "=v"(ua[0]) : "v"(h0[0]), "v"(h0[1]));
            asm("v_cvt_pk_bf16_f32 %0, %1, %2" : "=v"(ua[1]) : "v"(h0[2]), "v"(h0[3]));
            asm("v_cvt_pk_bf16_f32 %0, %1, %2" : "=v"(ua[2]) : "v"(h1[0]), "v"(h1[1]));
            asm("v_cvt_pk_bf16_f32 %0, %1, %2" : "=v"(ua[3]) : "v"(h1[2]), "v"(h1[3]));
            short8 af = *(short8*)&ua;
            #pragma unroll
            for (int nt = 0; nt < 6; ++nt) {
                int f = ch * 6 + nt;
                int row = f * 16 + lr;                   // (row&7) == lr&7 == hkey
                int blk = (ks * 4 + lg) ^ hkey;
                short8 bf_ = *(const short8*)(ldsW + buf * 12288 + row * 64 + blk * 8);
                acc[nt] = __builtin_amdgcn_mfma_f32_16x16x32_bf16(af, bf_, acc[nt], 0, 0, 0);
            }
        }
    };

    stage(0, 0);
    __syncthreads();
    for (int c = 0; c < 16; ++c) {
        if (c < 15) stage((c + 1) & 1, c + 1);
        compute(c & 1);
        __syncthreads();
    }

    #pragma unroll
    for (int nt = 0; nt < 6; ++nt)
        #pragma unroll
        for (int r = 0; r < 4; ++r)
            ldsO[(rt * 16 + lg * 4 + r) * 200 + ch * 96 + nt * 16 + lr] = acc[nt][r];
    __syncthreads();

    {   // Q and K: 512 threads, row = tid>>3 (0..63), 8 cols each
        const int row = tid >> 3;
        const int d0  = (tid & 7) * 8;
        const size_t grow = (size_t)(rowbase + row);
        short8 uq, uk;
        #pragma unroll
        for (int j = 0; j < 8; ++j) {
            uq[j] = (short)f2bf(ldsO[row * 200 + d0 + j]);
            uk[j] = (short)f2bf(ldsO[row * 200 + 64 + d0 + j]);
        }
        *(short8*)(Qb + grow * HD + d0) = uq;
        *(short8*)(Kb + grow * HD + (d0 ^ ((row & 7) << 3))) = uk;
    }
    {   // V: block covers exactly one 64-chunk; d = tid>>3, 4 u32 pairs each
        const int d  = tid >> 3;
        const int j  = tid & 7;
        const int b  = rowbase >> 12;
        const int ci = (rowbase & (SEQ - 1)) >> 6;
        unsigned short* vrow = Vt + (((size_t)b * 64 + ci) * 64 + d) * 64;
        const int dsw = (d & 7) << 3;
        #pragma unroll
        for (int k4 = 0; k4 < 4; ++k4) {
            int t0 = j * 2 + k4 * 16;            // even t in 0..62
            int tt = t0 & 31;
            int p0 = ((tt & 12) << 1) | (tt & 3) | ((tt & 16) >> 2);
            int e  = ((t0 & 32) | p0) ^ dsw;
            unsigned int val = (unsigned int)f2bf(ldsO[t0 * 200 + 128 + d])
                             | ((unsigned int)f2bf(ldsO[(t0 + 1) * 200 + 128 + d]) << 16);
            *(unsigned int*)(vrow + e) = val;
        }
    }
}

// ---------------------------------------------------------------------------
// Flash attention, LDS-COOPERATIVE v2: DOUBLE-BUFFERED staging + 4-way
// K-slice split with complementary-qb pairing.
// grid = 512 = 4b x 32qb x 4slice, 2 blocks/CU (16 waves/CU, LDS 32KB).
// bids>=256 (slices 2-3) remap qb -> 31-qb (bijective) so each CU's two
// co-resident blocks sum to ~16.5 chunks of work (was 2..64 imbalance).
// Per chunk: stage(i+1) issued BEFORE compute(i); single barrier/chunk
// (syncthreads drains vmcnt -> next chunk resident) — latency hidden.
// Softmax fixed m=0; exact additive merge of 4 slice partials.
// ---------------------------------------------------------------------------
__global__ __launch_bounds__(512, 2) void attn_kernel(
        const unsigned short* __restrict__ Qb, const unsigned short* __restrict__ Kb,
        const unsigned short* __restrict__ Vt,
        float* __restrict__ part_o, float* __restrict__ part_l) {
    __shared__ unsigned short ldsK[2 * 64 * 64];   // 16 KB (2 bufs, swizzled)
    __shared__ unsigned short ldsV[2 * 64 * 64];   // 16 KB
    const int tid  = threadIdx.x;
    const int w    = tid >> 6;
    const int lane = tid & 63;
    const int lr = lane & 15, lg = lane >> 4;

    const int bid   = blockIdx.x;
    const int b     = bid & 3;
    const int qbr   = (bid >> 2) & 31;
    const int slice = bid >> 7;                    // 0..3
    const int qb    = (slice >= 2) ? (31 - qbr) : qbr;   // complementary pairing
    const int qrow0 = qb * 128 + w * 16;           // this wave's 16 q-rows
    const int qwmax = qrow0 + 15;

    const unsigned short* __restrict__ Kp = Kb + (size_t)b * SEQ * HD;
    const unsigned short* __restrict__ Vp = Vt + (size_t)b * 64 * 4096;
    const unsigned short* __restrict__ Qp = Qb + ((size_t)b * SEQ + qrow0) * HD;

    short8 qf0 = *(const short8*)(Qp + lr * HD +      lg * 8);
    short8 qf1 = *(const short8*)(Qp + lr * HD + 32 + lg * 8);

    f32x4 o[4];
    #pragma unroll
    for (int nt = 0; nt < 4; ++nt) o[nt] = f32x4{0.f, 0.f, 0.f, 0.f};
    float lrun = 0.f;

    const int T  = 2 * (qb + 1);                   // total chunks for this q-block
    const int sz = (T + 3) >> 2;
    const int c0 = slice * sz;
    const int c1 = (c0 + sz < T) ? (c0 + sz) : T;
    const int nch = c1 - c0;
    const int swz = (lr & 7) << 3;

    auto stage = [&](int buf, int it) {
        const unsigned short* gk = Kp + (size_t)it * 64 * HD + w * 512 + lane * 8;
        const unsigned short* gv = Vp + (size_t)it * 4096 + w * 512 + lane * 8;
        __builtin_amdgcn_global_load_lds(
            (const __attribute__((address_space(1))) void*)gk,
            (__attribute__((address_space(3))) void*)(ldsK + buf * 4096 + w * 512), 16, 0, 0);
        __builtin_amdgcn_global_load_lds(
            (const __attribute__((address_space(1))) void*)gv,
            (__attribute__((address_space(3))) void*)(ldsV + buf * 4096 + w * 512), 16, 0, 0);
    };

    if (nch > 0) {
        stage(0, c0);
        __syncthreads();
        for (int i = 0; i < nch; ++i) {
            if (i + 1 < nch) stage((i + 1) & 1, c0 + i + 1);
            const int kvb = (c0 + i) * 64;
            const int bufo = (i & 1) * 4096;
            if (kvb <= qwmax) {
                f32x4 s0 = f32x4{0.f, 0.f, 0.f, 0.f};
                f32x4 s1 = f32x4{0.f, 0.f, 0.f, 0.f};
                f32x4 s2 = f32x4{0.f, 0.f, 0.f, 0.f};
                f32x4 s3 = f32x4{0.f, 0.f, 0.f, 0.f};
                {
                    short8 ka0 = *(const short8*)&ldsK[bufo + (0 * 16 + lr) * 64 + ((lg * 8)      ^ swz)];
                    short8 kb0 = *(const short8*)&ldsK[bufo + (0 * 16 + lr) * 64 + ((lg * 8 + 32) ^ swz)];
                    short8 ka1 = *(const short8*)&ldsK[bufo + (1 * 16 + lr) * 64 + ((lg * 8)      ^ swz)];
                    short8 kb1 = *(const short8*)&ldsK[bufo + (1 * 16 + lr) * 64 + ((lg * 8 + 32) ^ swz)];
                    short8 ka2 = *(const short8*)&ldsK[bufo + (2 * 16 + lr) * 64 + ((lg * 8)      ^ swz)];
                    short8 kb2 = *(const short8*)&ldsK[bufo + (2 * 16 + lr) * 64 + ((lg * 8 + 32) ^ swz)];
                    short8 ka3 = *(const short8*)&ldsK[bufo + (3 * 16 + lr) * 64 + ((lg * 8)      ^ swz)];
                    short8 kb3 = *(const short8*)&ldsK[bufo + (3 * 16 + lr) * 64 + ((lg * 8 + 32) ^ swz)];
                    s0 = __builtin_amdgcn_mfma_f32_16x16x32_bf16(ka0, qf0, s0, 0, 0, 0);
                    s0 = __builtin_amdgcn_mfma_f32_16x16x32_bf16(kb0, qf1, s0, 0, 0, 0);
                    s1 = __builtin_amdgcn_mfma_f32_16x16x32_bf16(ka1, qf0, s1, 0, 0, 0);
                    s1 = __builtin_amdgcn_mfma_f32_16x16x32_bf16(kb1, qf1, s1, 0, 0, 0);
                    s2 = __builtin_amdgcn_mfma_f32_16x16x32_bf16(ka2, qf0, s2, 0, 0, 0);
                    s2 = __builtin_amdgcn_mfma_f32_16x16x32_bf16(kb2, qf1, s2, 0, 0, 0);
                    s3 = __builtin_amdgcn_mfma_f32_16x16x32_bf16(ka3, qf0, s3, 0, 0, 0);
                    s3 = __builtin_amdgcn_mfma_f32_16x16x32_bf16(kb3, qf1, s3, 0, 0, 0);
                }

                if (kvb + 63 > qrow0) {          // mask if chunk passes FIRST row
                    const int qg = qrow0 + lr;
                    #pragma unroll
                    for (int r = 0; r < 4; ++r) {
                        int ky = kvb + lg * 4 + r;
                        if (ky      > qg) s0[r] = -1e30f;
                        if (ky + 16 > qg) s1[r] = -1e30f;
                        if (ky + 32 > qg) s2[r] = -1e30f;
                        if (ky + 48 > qg) s3[r] = -1e30f;
                    }
                }

                float p0[4], p1[4], p2[4], p3[4];
                #pragma unroll
                for (int r = 0; r < 4; ++r) {
                    p0[r] = exp2f(s0[r]);
                    p1[r] = exp2f(s1[r]);
                    p2[r] = exp2f(s2[r]);
                    p3[r] = exp2f(s3[r]);
                }
                lrun += ((p0[0] + p0[1]) + (p0[2] + p0[3])) + ((p1[0] + p1[1]) + (p1[2] + p1[3]))
                      + ((p2[0] + p2[1]) + (p2[2] + p2[3])) + ((p3[0] + p3[1]) + (p3[2] + p3[3]));

                uint4v ua, ub;
                asm("v_cvt_pk_bf16_f32 %0, %1, %2" : "=v"(ua[0]) : "v"(p0[0]), "v"(p0[1]));
                asm("v_cvt_pk_bf16_f32 %0, %1, %2" : "=v"(ua[1]) : "v"(p0[2]), "v"(p0[3]));
                asm("v_cvt_pk_bf16_f32 %0, %1, %2" : "=v"(ua[2]) : "v"(p1[0]), "v"(p1[1]));
                asm("v_cvt_pk_bf16_f32 %0, %1, %2" : "=v"(ua[3]) : "v"(p1[2]), "v"(p1[3]));
                asm("v_cvt_pk_bf16_f32 %0, %1, %2" : "=v"(ub[0]) : "v"(p2[0]), "v"(p2[1]));
                asm("v_cvt_pk_bf16_f32 %0, %1, %2" : "=v"(ub[1]) : "v"(p2[2]), "v"(p2[3]));
                asm("v_cvt_pk_bf16_f32 %0, %1, %2" : "=v"(ub[2]) : "v"(p3[0]), "v"(p3[1]));
                asm("v_cvt_pk_bf16_f32 %0, %1, %2" : "=v"(ub[3]) : "v"(p3[2]), "v"(p3[3]));
                short8 pba = *(short8*)&ua;      // keys kvb..kvb+31
                short8 pbb = *(short8*)&ub;      // keys kvb+32..kvb+63

                short8 va0 = *(const short8*)&ldsV[bufo + (0 * 16 + lr) * 64 + ((lg * 8)      ^ swz)];
                short8 vb0 = *(const short8*)&ldsV[bufo + (0 * 16 + lr) * 64 + ((lg * 8 + 32) ^ swz)];
                short8 va1 = *(const short8*)&ldsV[bufo + (1 * 16 + lr) * 64 + ((lg * 8)      ^ swz)];
                short8 vb1 = *(const short8*)&ldsV[bufo + (1 * 16 + lr) * 64 + ((lg * 8 + 32) ^ swz)];
                short8 va2 = *(const short8*)&ldsV[bufo + (2 * 16 + lr) * 64 + ((lg * 8)      ^ swz)];
                short8 vb2 = *(const short8*)&ldsV[bufo + (2 * 16 + lr) * 64 + ((lg * 8 + 32) ^ swz)];
                short8 va3 = *(const short8*)&ldsV[bufo + (3 * 16 + lr) * 64 + ((lg * 8)      ^ swz)];
                short8 vb3 = *(const short8*)&ldsV[bufo + (3 * 16 + lr) * 64 + ((lg * 8 + 32) ^ swz)];
                o[0] = __builtin_amdgcn_mfma_f32_16x16x32_bf16(va0, pba, o[0], 0, 0, 0);
                o[1] = __builtin_amdgcn_mfma_f32_16x16x32_bf16(va1, pba, o[1], 0, 0, 0);
                o[2] = __builtin_amdgcn_mfma_f32_16x16x32_bf16(va2, pba, o[2], 0, 0, 0);
                o[3] = __builtin_amdgcn_mfma_f32_16x16x32_bf16(va3, pba, o[3], 0, 0, 0);
                o[0] = __builtin_amdgcn_mfma_f32_16x16x32_bf16(vb0, pbb, o[0], 0, 0, 0);
                o[1] = __builtin_amdgcn_mfma_f32_16x16x32_bf16(vb1, pbb, o[1], 0, 0, 0);
                o[2] = __builtin_amdgcn_mfma_f32_16x16x32_bf16(vb2, pbb, o[2], 0, 0, 0);
                o[3] = __builtin_amdgcn_mfma_f32_16x16x32_bf16(vb3, pbb, o[3], 0, 0, 0);
            }
            __syncthreads();   // stage(i+1) drained; readers of buf(i) done
        }
    }

    // ---- per-q l across lane groups (exact: all terms share m=0)
    lrun += __shfl_xor(lrun, 16);
    lrun += __shfl_xor(lrun, 32);

    // ---- write slice partials: o[nt][r] = O[q=lr][d = nt*16+lg*4+r]
    const size_t prow = (((size_t)slice * 4 + b) * 32 + qb) * 128 + w * 16 + lr;
    float* po = part_o + prow * 64;
    #pragma unroll
    for (int nt = 0; nt < 4; ++nt)
        *(f32x4*)(po + nt * 16 + lg * 4) = o[nt];
    if (lg == 0) part_l[prow] = lrun;
}

// ---------------------------------------------------------------------------
// Merge: out = (sum_s o_s) / (sum_s l_s) over 4 slices.
// prow(s,row) = s*16384 + row  (row = b*4096 + q).
// ---------------------------------------------------------------------------
__global__ __launch_bounds__(256) void merge_kernel(
        const float* __restrict__ part_o, const float* __restrict__ part_l,
        float* __restrict__ out) {
    int idx = blockIdx.x * 256 + threadIdx.x;    // 0..262143
    int d4  = (idx & 15) * 4;
    int row = idx >> 4;                           // 0..16383 == b*4096 + q
    f32x4 a = f32x4{0.f, 0.f, 0.f, 0.f};
    float L = 0.f;
    #pragma unroll
    for (int s = 0; s < 4; ++s) {
        f32x4 p = *(const f32x4*)(part_o + ((size_t)s * 16384 + row) * 64 + d4);
        a[0] += p[0]; a[1] += p[1]; a[2] += p[2]; a[3] += p[3];
        L += part_l[s * 16384 + row];
    }
    float inv = 1.0f / L;
    f32x4 r;
    r[0] = a[0] * inv;
    r[1] = a[1] * inv;
    r[2] = a[2] * inv;
    r[3] = a[3] * inv;
    *(f32x4*)(out + (size_t)row * 64 + d4) = r;
}

// ---------------------------------------------------------------------------
extern "C" void kernel_launch(void* const* d_in, const int* in_sizes, int n_in,
                              void* d_out, int out_size, void* d_ws, size_t ws_size,
                              hipStream_t stream) {
    const float* H  = (const float*)d_in[0];
    const float* Wq = (const float*)d_in[1];
    const float* Wk = (const float*)d_in[2];
    const float* Wv = (const float*)d_in[3];
    float* out = (float*)d_out;

    // ws (bf16): Qb[1M] | Kb[1M] | Vt[1M] | Wt[196608]
    //   then (f32): part_o[4*16384*64] (16 MB) | part_l[4*16384] (256 KB)
    unsigned short* Qb = (unsigned short*)d_ws;
    unsigned short* Kb = Qb + (size_t)NB * SEQ * HD;
    unsigned short* Vt = Kb + (size_t)NB * SEQ * HD;
    unsigned short* Wt = Vt + (size_t)NB * SEQ * HD;
    float* part_o = (float*)(Wt + 3 * 65536);
    float* part_l = part_o + (size_t)4 * 16384 * 64;

    wprep_kernel<<<768, 256, 0, stream>>>(Wq, Wk, Wv, Wt);
    qkv_kernel<<<NB * SEQ / 64, 512, 0, stream>>>(H, Wt, Qb, Kb, Vt);
    attn_kernel<<<512, 512, 0, stream>>>(Qb, Kb, Vt, part_o, part_l);
    merge_kernel<<<1024, 256, 0, stream>>>(part_o, part_l, out);
}

// Round 18
// 52.646 us; speedup vs baseline: 5.0057x; 1.0444x over previous
//
#include <hip/hip_runtime.h>
#include <hip/hip_bf16.h>
#include <stdint.h>

#define SEQ 4096
#define EMB 1024
#define HD  64
#define NB  4

typedef __attribute__((ext_vector_type(8))) short short8;   // 8 x bf16 (4 VGPRs)
typedef __attribute__((ext_vector_type(4))) float f32x4;
typedef __attribute__((ext_vector_type(4))) unsigned int uint4v;

// RNE float -> bf16 bits (no NaN inputs here)
static __device__ __forceinline__ unsigned short f2bf(float f) {
    unsigned int u = __float_as_uint(f);
    u += 0x7fffu + ((u >> 16) & 1u);
    return (unsigned short)(u >> 16);
}

// ---------------------------------------------------------------------------
// Prep: Wt[m][d][e] = bf16(W_m[e][d]),  m in {q,k,v}.  3*64*1024 elements.
// Wq is pre-scaled by log2(e)/sqrt(64) so attn needs no scale multiply.
// ---------------------------------------------------------------------------
__global__ __launch_bounds__(256) void wprep_kernel(
        const float* __restrict__ Wq, const float* __restrict__ Wk,
        const float* __restrict__ Wv, unsigned short* __restrict__ Wt) {
    int idx = blockIdx.x * 256 + threadIdx.x;       // < 3*65536
    int m = idx >> 16;
    int r = idx & 65535;
    int d = r >> 10;
    int e = r & 1023;
    const float* W = (m == 0) ? Wq : (m == 1) ? Wk : Wv;
    float v = W[e * HD + d];
    if (m == 0) v *= 0.18033688011111793f;          // log2(e)/sqrt(64)
    Wt[idx] = f2bf(v);
}

// ---------------------------------------------------------------------------
// QKV v3 — LDS-cooperative + 3-BUFFER COUNTED-VMCNT PIPELINE (T3/T4).
// Same tiling/layouts as v2 (64-row blocks, 8 waves = 4rt x 2ch, swizzled
// gload_lds staging). Change: raw s_barrier (no vmcnt drain) + counted
// s_waitcnt vmcnt(N): 5 loads/wave/chunk, steady-state N=10 (2 chunks in
// flight), tail 5 -> 0. Buffer reuse hazard covered by the post-compute
// barrier (stage(c+3) writes buf c%3 only after all waves read it).
// ---------------------------------------------------------------------------
__global__ __launch_bounds__(512, 4) void qkv_kernel(
        const float* __restrict__ H, const unsigned short* __restrict__ Wt,
        unsigned short* __restrict__ Qb, unsigned short* __restrict__ Kb,
        unsigned short* __restrict__ Vt) {
    __shared__ unsigned char smem[122880];           // 120 KB: 3 x (24KB W + 16KB H)
    unsigned short* ldsW = (unsigned short*)smem;            // [3][192][64] bf16
    float* ldsH = (float*)(smem + 3 * 24576);                // [3][64][64] f32
    float* ldsO = (float*)smem;                              // epilogue overlay [64][200]

    const int tid  = threadIdx.x;
    const int w    = tid >> 6;
    const int lane = tid & 63;
    const int lr = lane & 15, lg = lane >> 4;
    const int rt = w >> 1, ch = w & 1;
    const int rowbase = blockIdx.x * 64;

    f32x4 acc[6];
    #pragma unroll
    for (int nt = 0; nt < 6; ++nt) acc[nt] = f32x4{0.f, 0.f, 0.f, 0.f};

    auto stage = [&](int buf, int c) {
        const int kk0 = c * 64;
        #pragma unroll
        for (int ii = 0; ii < 3; ++ii) {
            int i = w * 3 + ii;
            int rowidx = 8 * i + (lane >> 3);            // 0..191  (m*64+d)
            int sb = (lane & 7) ^ (lane >> 3);           // src 16B-block ^ (row&7)
            const unsigned short* src = Wt + rowidx * EMB + kk0 + sb * 8;
            __builtin_amdgcn_global_load_lds(
                (const __attribute__((address_space(1))) void*)src,
                (__attribute__((address_space(3))) void*)(ldsW + buf * 12288 + i * 512 + lane * 8),
                16, 0, 0);
        }
        #pragma unroll
        for (int ii = 0; ii < 2; ++ii) {
            int i = w * 2 + ii;
            int rowidx = 4 * i + (lane >> 4);            // 0..63
            int key = rowidx & 7;
            int sb = (lane & 15) ^ key;                  // src 16B-block ^ (row&7)
            const float* src = H + (size_t)(rowbase + rowidx) * EMB + kk0 + sb * 4;
            __builtin_amdgcn_global_load_lds(
                (const __attribute__((address_space(1))) void*)src,
                (__attribute__((address_space(3))) void*)(ldsH + buf * 4096 + i * 256 + lane * 4),
                16, 0, 0);
        }
    };

    auto compute = [&](int buf) {
        const int hrow = rt * 16 + lr;
        const int hkey = lr & 7;
        #pragma unroll
        for (int ks = 0; ks < 2; ++ks) {
            int b0 = ks * 8 + lg * 2;
            f32x4 h0 = *(const f32x4*)(ldsH + buf * 4096 + hrow * 64 + ((b0 ^ hkey) * 4));
            f32x4 h1 = *(const f32x4*)(ldsH + buf * 4096 + hrow * 64 + (((b0 + 1) ^ hkey) * 4));
            uint4v ua;
            asm("v_cvt_pk_bf16_f32 %0, %1, %2" : "=v"(ua[0]) : "v"(h0[0]), "v"(h0[1]));
            asm("v_cvt_pk_bf16_f32 %0, %1, %2" : "=v"(ua[1]) : "v"(h0[2]), "v"(h0[3]));
            asm("v_cvt_pk_bf16_f32 %0, %1, %2" : "=v"(ua[2]) : "v"(h1[0]), "v"(h1[1]));
            asm("v_cvt_pk_bf16_f32 %0, %1, %2" : "=v"(ua[3]) : "v"(h1[2]), "v"(h1[3]));
            short8 af = *(short8*)&ua;
            #pragma unroll
            for (int nt = 0; nt < 6; ++nt) {
                int f = ch * 6 + nt;
                int row = f * 16 + lr;                   // (row&7) == lr&7 == hkey
                int blk = (ks * 4 + lg) ^ hkey;
                short8 bf_ = *(const short8*)(ldsW + buf * 12288 + row * 64 + blk * 8);
                acc[nt] = __builtin_amdgcn_mfma_f32_16x16x32_bf16(af, bf_, acc[nt], 0, 0, 0);
            }
        }
    };

    stage(0, 0);
    stage(1, 1);
    for (int c = 0; c < 16; ++c) {
        if (c + 2 < 16) stage((c + 2) % 3, c + 2);
        // wait for chunk c's loads: remaining = 5 * (#staged chunks beyond c)
        if (c <= 13)      asm volatile("s_waitcnt vmcnt(10)" ::: "memory");
        else if (c == 14) asm volatile("s_waitcnt vmcnt(5)"  ::: "memory");
        else              asm volatile("s_waitcnt vmcnt(0)"  ::: "memory");
        __builtin_amdgcn_sched_barrier(0);
        __builtin_amdgcn_s_barrier();
        compute(c % 3);
        __builtin_amdgcn_s_barrier();   // readers of buf c%3 done before reuse
    }

    #pragma unroll
    for (int nt = 0; nt < 6; ++nt)
        #pragma unroll
        for (int r = 0; r < 4; ++r)
            ldsO[(rt * 16 + lg * 4 + r) * 200 + ch * 96 + nt * 16 + lr] = acc[nt][r];
    __syncthreads();

    {   // Q and K: 512 threads, row = tid>>3 (0..63), 8 cols each
        const int row = tid >> 3;
        const int d0  = (tid & 7) * 8;
        const size_t grow = (size_t)(rowbase + row);
        short8 uq, uk;
        #pragma unroll
        for (int j = 0; j < 8; ++j) {
            uq[j] = (short)f2bf(ldsO[row * 200 + d0 + j]);
            uk[j] = (short)f2bf(ldsO[row * 200 + 64 + d0 + j]);
        }
        *(short8*)(Qb + grow * HD + d0) = uq;
        *(short8*)(Kb + grow * HD + (d0 ^ ((row & 7) << 3))) = uk;
    }
    {   // V: block covers exactly one 64-chunk; d = tid>>3, 4 u32 pairs each
        const int d  = tid >> 3;
        const int j  = tid & 7;
        const int b  = rowbase >> 12;
        const int ci = (rowbase & (SEQ - 1)) >> 6;
        unsigned short* vrow = Vt + (((size_t)b * 64 + ci) * 64 + d) * 64;
        const int dsw = (d & 7) << 3;
        #pragma unroll
        for (int k4 = 0; k4 < 4; ++k4) {
            int t0 = j * 2 + k4 * 16;            // even t in 0..62
            int tt = t0 & 31;
            int p0 = ((tt & 12) << 1) | (tt & 3) | ((tt & 16) >> 2);
            int e  = ((t0 & 32) | p0) ^ dsw;
            unsigned int val = (unsigned int)f2bf(ldsO[t0 * 200 + 128 + d])
                             | ((unsigned int)f2bf(ldsO[(t0 + 1) * 200 + 128 + d]) << 16);
            *(unsigned int*)(vrow + e) = val;
        }
    }
}

// ---------------------------------------------------------------------------
// Flash attention v3: LDS-cooperative + 3-BUFFER COUNTED-VMCNT PIPELINE.
// Structure/layouts/slicing identical to R17 (4-way slices, complementary
// qb pairing, m=0 softmax, exact additive merge). Change: raw s_barrier +
// counted vmcnt (2 loads/wave/chunk -> steady N=4, tail 2 -> 0).
// ---------------------------------------------------------------------------
__global__ __launch_bounds__(512, 2) void attn_kernel(
        const unsigned short* __restrict__ Qb, const unsigned short* __restrict__ Kb,
        const unsigned short* __restrict__ Vt,
        float* __restrict__ part_o, float* __restrict__ part_l) {
    __shared__ unsigned short ldsK[3 * 64 * 64];   // 24 KB (3 bufs, swizzled)
    __shared__ unsigned short ldsV[3 * 64 * 64];   // 24 KB
    const int tid  = threadIdx.x;
    const int w    = tid >> 6;
    const int lane = tid & 63;
    const int lr = lane & 15, lg = lane >> 4;

    const int bid   = blockIdx.x;
    const int b     = bid & 3;
    const int qbr   = (bid >> 2) & 31;
    const int slice = bid >> 7;                    // 0..3
    const int qb    = (slice >= 2) ? (31 - qbr) : qbr;   // complementary pairing
    const int qrow0 = qb * 128 + w * 16;           // this wave's 16 q-rows
    const int qwmax = qrow0 + 15;

    const unsigned short* __restrict__ Kp = Kb + (size_t)b * SEQ * HD;
    const unsigned short* __restrict__ Vp = Vt + (size_t)b * 64 * 4096;
    const unsigned short* __restrict__ Qp = Qb + ((size_t)b * SEQ + qrow0) * HD;

    short8 qf0 = *(const short8*)(Qp + lr * HD +      lg * 8);
    short8 qf1 = *(const short8*)(Qp + lr * HD + 32 + lg * 8);

    f32x4 o[4];
    #pragma unroll
    for (int nt = 0; nt < 4; ++nt) o[nt] = f32x4{0.f, 0.f, 0.f, 0.f};
    float lrun = 0.f;

    const int T  = 2 * (qb + 1);                   // total chunks for this q-block
    const int sz = (T + 3) >> 2;
    const int c0 = slice * sz;
    const int c1 = (c0 + sz < T) ? (c0 + sz) : T;
    const int nch = c1 - c0;
    const int swz = (lr & 7) << 3;

    auto stage = [&](int buf, int it) {
        const unsigned short* gk = Kp + (size_t)it * 64 * HD + w * 512 + lane * 8;
        const unsigned short* gv = Vp + (size_t)it * 4096 + w * 512 + lane * 8;
        __builtin_amdgcn_global_load_lds(
            (const __attribute__((address_space(1))) void*)gk,
            (__attribute__((address_space(3))) void*)(ldsK + buf * 4096 + w * 512), 16, 0, 0);
        __builtin_amdgcn_global_load_lds(
            (const __attribute__((address_space(1))) void*)gv,
            (__attribute__((address_space(3))) void*)(ldsV + buf * 4096 + w * 512), 16, 0, 0);
    };

    if (nch > 0) {
        stage(0, c0);
        if (nch > 1) stage(1, c0 + 1);
        for (int i = 0; i < nch; ++i) {
            if (i + 2 < nch) stage((i + 2) % 3, c0 + i + 2);
            // wait chunk i: remaining = 2 * (#staged beyond i)
            if (i + 2 < nch)      asm volatile("s_waitcnt vmcnt(4)" ::: "memory");
            else if (i + 1 < nch) asm volatile("s_waitcnt vmcnt(2)" ::: "memory");
            else                  asm volatile("s_waitcnt vmcnt(0)" ::: "memory");
            __builtin_amdgcn_sched_barrier(0);
            __builtin_amdgcn_s_barrier();

            const int kvb = (c0 + i) * 64;
            const int bufo = (i % 3) * 4096;
            if (kvb <= qwmax) {
                f32x4 s0 = f32x4{0.f, 0.f, 0.f, 0.f};
                f32x4 s1 = f32x4{0.f, 0.f, 0.f, 0.f};
                f32x4 s2 = f32x4{0.f, 0.f, 0.f, 0.f};
                f32x4 s3 = f32x4{0.f, 0.f, 0.f, 0.f};
                {
                    short8 ka0 = *(const short8*)&ldsK[bufo + (0 * 16 + lr) * 64 + ((lg * 8)      ^ swz)];
                    short8 kb0 = *(const short8*)&ldsK[bufo + (0 * 16 + lr) * 64 + ((lg * 8 + 32) ^ swz)];
                    short8 ka1 = *(const short8*)&ldsK[bufo + (1 * 16 + lr) * 64 + ((lg * 8)      ^ swz)];
                    short8 kb1 = *(const short8*)&ldsK[bufo + (1 * 16 + lr) * 64 + ((lg * 8 + 32) ^ swz)];
                    short8 ka2 = *(const short8*)&ldsK[bufo + (2 * 16 + lr) * 64 + ((lg * 8)      ^ swz)];
                    short8 kb2 = *(const short8*)&ldsK[bufo + (2 * 16 + lr) * 64 + ((lg * 8 + 32) ^ swz)];
                    short8 ka3 = *(const short8*)&ldsK[bufo + (3 * 16 + lr) * 64 + ((lg * 8)      ^ swz)];
                    short8 kb3 = *(const short8*)&ldsK[bufo + (3 * 16 + lr) * 64 + ((lg * 8 + 32) ^ swz)];
                    s0 = __builtin_amdgcn_mfma_f32_16x16x32_bf16(ka0, qf0, s0, 0, 0, 0);
                    s0 = __builtin_amdgcn_mfma_f32_16x16x32_bf16(kb0, qf1, s0, 0, 0, 0);
                    s1 = __builtin_amdgcn_mfma_f32_16x16x32_bf16(ka1, qf0, s1, 0, 0, 0);
                    s1 = __builtin_amdgcn_mfma_f32_16x16x32_bf16(kb1, qf1, s1, 0, 0, 0);
                    s2 = __builtin_amdgcn_mfma_f32_16x16x32_bf16(ka2, qf0, s2, 0, 0, 0);
                    s2 = __builtin_amdgcn_mfma_f32_16x16x32_bf16(kb2, qf1, s2, 0, 0, 0);
                    s3 = __builtin_amdgcn_mfma_f32_16x16x32_bf16(ka3, qf0, s3, 0, 0, 0);
                    s3 = __builtin_amdgcn_mfma_f32_16x16x32_bf16(kb3, qf1, s3, 0, 0, 0);
                }

                if (kvb + 63 > qrow0) {          // mask if chunk passes FIRST row
                    const int qg = qrow0 + lr;
                    #pragma unroll
                    for (int r = 0; r < 4; ++r) {
                        int ky = kvb + lg * 4 + r;
                        if (ky      > qg) s0[r] = -1e30f;
                        if (ky + 16 > qg) s1[r] = -1e30f;
                        if (ky + 32 > qg) s2[r] = -1e30f;
                        if (ky + 48 > qg) s3[r] = -1e30f;
                    }
                }

                float p0[4], p1[4], p2[4], p3[4];
                #pragma unroll
                for (int r = 0; r < 4; ++r) {
                    p0[r] = exp2f(s0[r]);
                    p1[r] = exp2f(s1[r]);
                    p2[r] = exp2f(s2[r]);
                    p3[r] = exp2f(s3[r]);
                }
                lrun += ((p0[0] + p0[1]) + (p0[2] + p0[3])) + ((p1[0] + p1[1]) + (p1[2] + p1[3]))
                      + ((p2[0] + p2[1]) + (p2[2] + p2[3])) + ((p3[0] + p3[1]) + (p3[2] + p3[3]));

                uint4v ua, ub;
                asm("v_cvt_pk_bf16_f32 %0, %1, %2" : "=v"(ua[0]) : "v"(p0[0]), "v"(p0[1]));
                asm("v_cvt_pk_bf16_f32 %0, %1, %2" : "=v"(ua[1]) : "v"(p0[2]), "v"(p0[3]));
                asm("v_cvt_pk_bf16_f32 %0, %1, %2" : "=v"(ua[2]) : "v"(p1[0]), "v"(p1[1]));
                asm("v_cvt_pk_bf16_f32 %0, %1, %2" : "=v"(ua[3]) : "v"(p1[2]), "v"(p1[3]));
                asm("v_cvt_pk_bf16_f32 %0, %1, %2" : "=v"(ub[0]) : "v"(p2[0]), "v"(p2[1]));
                asm("v_cvt_pk_bf16_f32 %0, %1, %2" : "=v"(ub[1]) : "v"(p2[2]), "v"(p2[3]));
                asm("v_cvt_pk_bf16_f32 %0, %1, %2" : "=v"(ub[2]) : "v"(p3[0]), "v"(p3[1]));
                asm("v_cvt_pk_bf16_f32 %0, %1, %2" : "=v"(ub[3]) : "v"(p3[2]), "v"(p3[3]));
                short8 pba = *(short8*)&ua;      // keys kvb..kvb+31
                short8 pbb = *(short8*)&ub;      // keys kvb+32..kvb+63

                short8 va0 = *(const short8*)&ldsV[bufo + (0 * 16 + lr) * 64 + ((lg * 8)      ^ swz)];
                short8 vb0 = *(const short8*)&ldsV[bufo + (0 * 16 + lr) * 64 + ((lg * 8 + 32) ^ swz)];
                short8 va1 = *(const short8*)&ldsV[bufo + (1 * 16 + lr) * 64 + ((lg * 8)      ^ swz)];
                short8 vb1 = *(const short8*)&ldsV[bufo + (1 * 16 + lr) * 64 + ((lg * 8 + 32) ^ swz)];
                short8 va2 = *(const short8*)&ldsV[bufo + (2 * 16 + lr) * 64 + ((lg * 8)      ^ swz)];
                short8 vb2 = *(const short8*)&ldsV[bufo + (2 * 16 + lr) * 64 + ((lg * 8 + 32) ^ swz)];
                short8 va3 = *(const short8*)&ldsV[bufo + (3 * 16 + lr) * 64 + ((lg * 8)      ^ swz)];
                short8 vb3 = *(const short8*)&ldsV[bufo + (3 * 16 + lr) * 64 + ((lg * 8 + 32) ^ swz)];
                o[0] = __builtin_amdgcn_mfma_f32_16x16x32_bf16(va0, pba, o[0], 0, 0, 0);
                o[1] = __builtin_amdgcn_mfma_f32_16x16x32_bf16(va1, pba, o[1], 0, 0, 0);
                o[2] = __builtin_amdgcn_mfma_f32_16x16x32_bf16(va2, pba, o[2], 0, 0, 0);
                o[3] = __builtin_amdgcn_mfma_f32_16x16x32_bf16(va3, pba, o[3], 0, 0, 0);
                o[0] = __builtin_amdgcn_mfma_f32_16x16x32_bf16(vb0, pbb, o[0], 0, 0, 0);
                o[1] = __builtin_amdgcn_mfma_f32_16x16x32_bf16(vb1, pbb, o[1], 0, 0, 0);
                o[2] = __builtin_amdgcn_mfma_f32_16x16x32_bf16(vb2, pbb, o[2], 0, 0, 0);
                o[3] = __builtin_amdgcn_mfma_f32_16x16x32_bf16(vb3, pbb, o[3], 0, 0, 0);
            }
            __builtin_amdgcn_s_barrier();   // readers of buf i%3 done before reuse
        }
    }

    // ---- per-q l across lane groups (exact: all terms share m=0)
    lrun += __shfl_xor(lrun, 16);
    lrun += __shfl_xor(lrun, 32);

    // ---- write slice partials: o[nt][r] = O[q=lr][d = nt*16+lg*4+r]
    const size_t prow = (((size_t)slice * 4 + b) * 32 + qb) * 128 + w * 16 + lr;
    float* po = part_o + prow * 64;
    #pragma unroll
    for (int nt = 0; nt < 4; ++nt)
        *(f32x4*)(po + nt * 16 + lg * 4) = o[nt];
    if (lg == 0) part_l[prow] = lrun;
}

// ---------------------------------------------------------------------------
// Merge: out = (sum_s o_s) / (sum_s l_s) over 4 slices.
// ---------------------------------------------------------------------------
__global__ __launch_bounds__(256) void merge_kernel(
        const float* __restrict__ part_o, const float* __restrict__ part_l,
        float* __restrict__ out) {
    int idx = blockIdx.x * 256 + threadIdx.x;    // 0..262143
    int d4  = (idx & 15) * 4;
    int row = idx >> 4;                           // 0..16383 == b*4096 + q
    f32x4 a = f32x4{0.f, 0.f, 0.f, 0.f};
    float L = 0.f;
    #pragma unroll
    for (int s = 0; s < 4; ++s) {
        f32x4 p = *(const f32x4*)(part_o + ((size_t)s * 16384 + row) * 64 + d4);
        a[0] += p[0]; a[1] += p[1]; a[2] += p[2]; a[3] += p[3];
        L += part_l[s * 16384 + row];
    }
    float inv = 1.0f / L;
    f32x4 r;
    r[0] = a[0] * inv;
    r[1] = a[1] * inv;
    r[2] = a[2] * inv;
    r[3] = a[3] * inv;
    *(f32x4*)(out + (size_t)row * 64 + d4) = r;
}

// ---------------------------------------------------------------------------
extern "C" void kernel_launch(void* const* d_in, const int* in_sizes, int n_in,
                              void* d_out, int out_size, void* d_ws, size_t ws_size,
                              hipStream_t stream) {
    const float* H  = (const float*)d_in[0];
    const float* Wq = (const float*)d_in[1];
    const float* Wk = (const float*)d_in[2];
    const float* Wv = (const float*)d_in[3];
    float* out = (float*)d_out;

    // ws (bf16): Qb[1M] | Kb[1M] | Vt[1M] | Wt[196608]
    //   then (f32): part_o[4*16384*64] (16 MB) | part_l[4*16384] (256 KB)
    unsigned short* Qb = (unsigned short*)d_ws;
    unsigned short* Kb = Qb + (size_t)NB * SEQ * HD;
    unsigned short* Vt = Kb + (size_t)NB * SEQ * HD;
    unsigned short* Wt = Vt + (size_t)NB * SEQ * HD;
    float* part_o = (float*)(Wt + 3 * 65536);
    float* part_l = part_o + (size_t)4 * 16384 * 64;

    wprep_kernel<<<768, 256, 0, stream>>>(Wq, Wk, Wv, Wt);
    qkv_kernel<<<NB * SEQ / 64, 512, 0, stream>>>(H, Wt, Qb, Kb, Vt);
    attn_kernel<<<512, 512, 0, stream>>>(Qb, Kb, Vt, part_o, part_l);
    merge_kernel<<<1024, 256, 0, stream>>>(part_o, part_l, out);
}

// Round 19
// 50.445 us; speedup vs baseline: 5.2242x; 1.0436x over previous
//
#include <hip/hip_runtime.h>
#include <hip/hip_bf16.h>
#include <stdint.h>

#define SEQ 4096
#define EMB 1024
#define HD  64
#define NB  4

typedef __attribute__((ext_vector_type(8))) short short8;   // 8 x bf16 (4 VGPRs)
typedef __attribute__((ext_vector_type(4))) float f32x4;
typedef __attribute__((ext_vector_type(4))) unsigned int uint4v;

// RNE float -> bf16 bits (no NaN inputs here)
static __device__ __forceinline__ unsigned short f2bf(float f) {
    unsigned int u = __float_as_uint(f);
    u += 0x7fffu + ((u >> 16) & 1u);
    return (unsigned short)(u >> 16);
}

// ---------------------------------------------------------------------------
// Prep: Wt[m][d][e] = bf16(W_m[e][d]),  m in {q,k,v}.  3*64*1024 elements.
// Wq is pre-scaled by log2(e)/sqrt(64) so attn needs no scale multiply.
// ---------------------------------------------------------------------------
__global__ __launch_bounds__(256) void wprep_kernel(
        const float* __restrict__ Wq, const float* __restrict__ Wk,
        const float* __restrict__ Wv, unsigned short* __restrict__ Wt) {
    int idx = blockIdx.x * 256 + threadIdx.x;       // < 3*65536
    int m = idx >> 16;
    int r = idx & 65535;
    int d = r >> 10;
    int e = r & 1023;
    const float* W = (m == 0) ? Wq : (m == 1) ? Wk : Wv;
    float v = W[e * HD + d];
    if (m == 0) v *= 0.18033688011111793f;          // log2(e)/sqrt(64)
    Wt[idx] = f2bf(v);
}

// ---------------------------------------------------------------------------
// QKV v3 — LDS-cooperative + 3-buffer counted-vmcnt pipeline (unchanged R18).
// ---------------------------------------------------------------------------
__global__ __launch_bounds__(512, 4) void qkv_kernel(
        const float* __restrict__ H, const unsigned short* __restrict__ Wt,
        unsigned short* __restrict__ Qb, unsigned short* __restrict__ Kb,
        unsigned short* __restrict__ Vt) {
    __shared__ unsigned char smem[122880];           // 120 KB: 3 x (24KB W + 16KB H)
    unsigned short* ldsW = (unsigned short*)smem;            // [3][192][64] bf16
    float* ldsH = (float*)(smem + 3 * 24576);                // [3][64][64] f32
    float* ldsO = (float*)smem;                              // epilogue overlay [64][200]

    const int tid  = threadIdx.x;
    const int w    = tid >> 6;
    const int lane = tid & 63;
    const int lr = lane & 15, lg = lane >> 4;
    const int rt = w >> 1, ch = w & 1;
    const int rowbase = blockIdx.x * 64;

    f32x4 acc[6];
    #pragma unroll
    for (int nt = 0; nt < 6; ++nt) acc[nt] = f32x4{0.f, 0.f, 0.f, 0.f};

    auto stage = [&](int buf, int c) {
        const int kk0 = c * 64;
        #pragma unroll
        for (int ii = 0; ii < 3; ++ii) {
            int i = w * 3 + ii;
            int rowidx = 8 * i + (lane >> 3);            // 0..191  (m*64+d)
            int sb = (lane & 7) ^ (lane >> 3);           // src 16B-block ^ (row&7)
            const unsigned short* src = Wt + rowidx * EMB + kk0 + sb * 8;
            __builtin_amdgcn_global_load_lds(
                (const __attribute__((address_space(1))) void*)src,
                (__attribute__((address_space(3))) void*)(ldsW + buf * 12288 + i * 512 + lane * 8),
                16, 0, 0);
        }
        #pragma unroll
        for (int ii = 0; ii < 2; ++ii) {
            int i = w * 2 + ii;
            int rowidx = 4 * i + (lane >> 4);            // 0..63
            int key = rowidx & 7;
            int sb = (lane & 15) ^ key;                  // src 16B-block ^ (row&7)
            const float* src = H + (size_t)(rowbase + rowidx) * EMB + kk0 + sb * 4;
            __builtin_amdgcn_global_load_lds(
                (const __attribute__((address_space(1))) void*)src,
                (__attribute__((address_space(3))) void*)(ldsH + buf * 4096 + i * 256 + lane * 4),
                16, 0, 0);
        }
    };

    auto compute = [&](int buf) {
        const int hrow = rt * 16 + lr;
        const int hkey = lr & 7;
        #pragma unroll
        for (int ks = 0; ks < 2; ++ks) {
            int b0 = ks * 8 + lg * 2;
            f32x4 h0 = *(const f32x4*)(ldsH + buf * 4096 + hrow * 64 + ((b0 ^ hkey) * 4));
            f32x4 h1 = *(const f32x4*)(ldsH + buf * 4096 + hrow * 64 + (((b0 + 1) ^ hkey) * 4));
            uint4v ua;
            asm("v_cvt_pk_bf16_f32 %0, %1, %2" : "=v"(ua[0]) : "v"(h0[0]), "v"(h0[1]));
            asm("v_cvt_pk_bf16_f32 %0, %1, %2" : "=v"(ua[1]) : "v"(h0[2]), "v"(h0[3]));
            asm("v_cvt_pk_bf16_f32 %0, %1, %2" : "=v"(ua[2]) : "v"(h1[0]), "v"(h1[1]));
            asm("v_cvt_pk_bf16_f32 %0, %1, %2" : "=v"(ua[3]) : "v"(h1[2]), "v"(h1[3]));
            short8 af = *(short8*)&ua;
            #pragma unroll
            for (int nt = 0; nt < 6; ++nt) {
                int f = ch * 6 + nt;
                int row = f * 16 + lr;                   // (row&7) == lr&7 == hkey
                int blk = (ks * 4 + lg) ^ hkey;
                short8 bf_ = *(const short8*)(ldsW + buf * 12288 + row * 64 + blk * 8);
                acc[nt] = __builtin_amdgcn_mfma_f32_16x16x32_bf16(af, bf_, acc[nt], 0, 0, 0);
            }
        }
    };

    stage(0, 0);
    stage(1, 1);
    for (int c = 0; c < 16; ++c) {
        if (c + 2 < 16) stage((c + 2) % 3, c + 2);
        if (c <= 13)      asm volatile("s_waitcnt vmcnt(10)" ::: "memory");
        else if (c == 14) asm volatile("s_waitcnt vmcnt(5)"  ::: "memory");
        else              asm volatile("s_waitcnt vmcnt(0)"  ::: "memory");
        __builtin_amdgcn_sched_barrier(0);
        __builtin_amdgcn_s_barrier();
        compute(c % 3);
        __builtin_amdgcn_s_barrier();   // readers of buf c%3 done before reuse
    }

    #pragma unroll
    for (int nt = 0; nt < 6; ++nt)
        #pragma unroll
        for (int r = 0; r < 4; ++r)
            ldsO[(rt * 16 + lg * 4 + r) * 200 + ch * 96 + nt * 16 + lr] = acc[nt][r];
    __syncthreads();

    {   // Q and K: 512 threads, row = tid>>3 (0..63), 8 cols each
        const int row = tid >> 3;
        const int d0  = (tid & 7) * 8;
        const size_t grow = (size_t)(rowbase + row);
        short8 uq, uk;
        #pragma unroll
        for (int j = 0; j < 8; ++j) {
            uq[j] = (short)f2bf(ldsO[row * 200 + d0 + j]);
            uk[j] = (short)f2bf(ldsO[row * 200 + 64 + d0 + j]);
        }
        *(short8*)(Qb + grow * HD + d0) = uq;
        *(short8*)(Kb + grow * HD + (d0 ^ ((row & 7) << 3))) = uk;
    }
    {   // V: block covers exactly one 64-chunk; d = tid>>3, 4 u32 pairs each
        const int d  = tid >> 3;
        const int j  = tid & 7;
        const int b  = rowbase >> 12;
        const int ci = (rowbase & (SEQ - 1)) >> 6;
        unsigned short* vrow = Vt + (((size_t)b * 64 + ci) * 64 + d) * 64;
        const int dsw = (d & 7) << 3;
        #pragma unroll
        for (int k4 = 0; k4 < 4; ++k4) {
            int t0 = j * 2 + k4 * 16;            // even t in 0..62
            int tt = t0 & 31;
            int p0 = ((tt & 12) << 1) | (tt & 3) | ((tt & 16) >> 2);
            int e  = ((t0 & 32) | p0) ^ dsw;
            unsigned int val = (unsigned int)f2bf(ldsO[t0 * 200 + 128 + d])
                             | ((unsigned int)f2bf(ldsO[(t0 + 1) * 200 + 128 + d]) << 16);
            *(unsigned int*)(vrow + e) = val;
        }
    }
}

// ---------------------------------------------------------------------------
// Flash attention v4: 2-CHUNK BARRIER INTERVALS (KVBLK=128 per interval).
// Same slicing/layouts/softmax as R18. Change: stage a chunk PAIR into one
// of 2 double-buffers (LDS 2 x 2 x 8KB per array = 64 KB total, 2 blocks/CU);
// compute 32 MFMAs + 2x softmax between barrier pairs -> barrier count per
// output halved, longer compute covers next pair's staging.
// Counted vmcnt: 4 loads/wave/interval steady, 2 for odd tail, 0 final.
// ---------------------------------------------------------------------------
__global__ __launch_bounds__(512, 2) void attn_kernel(
        const unsigned short* __restrict__ Qb, const unsigned short* __restrict__ Kb,
        const unsigned short* __restrict__ Vt,
        float* __restrict__ part_o, float* __restrict__ part_l) {
    __shared__ unsigned short ldsK[2 * 2 * 4096];  // 32 KB: [buf][pairslot][64x64]
    __shared__ unsigned short ldsV[2 * 2 * 4096];  // 32 KB
    const int tid  = threadIdx.x;
    const int w    = tid >> 6;
    const int lane = tid & 63;
    const int lr = lane & 15, lg = lane >> 4;

    const int bid   = blockIdx.x;
    const int b     = bid & 3;
    const int qbr   = (bid >> 2) & 31;
    const int slice = bid >> 7;                    // 0..3
    const int qb    = (slice >= 2) ? (31 - qbr) : qbr;   // complementary pairing
    const int qrow0 = qb * 128 + w * 16;           // this wave's 16 q-rows
    const int qwmax = qrow0 + 15;

    const unsigned short* __restrict__ Kp = Kb + (size_t)b * SEQ * HD;
    const unsigned short* __restrict__ Vp = Vt + (size_t)b * 64 * 4096;
    const unsigned short* __restrict__ Qp = Qb + ((size_t)b * SEQ + qrow0) * HD;

    short8 qf0 = *(const short8*)(Qp + lr * HD +      lg * 8);
    short8 qf1 = *(const short8*)(Qp + lr * HD + 32 + lg * 8);

    f32x4 o[4];
    #pragma unroll
    for (int nt = 0; nt < 4; ++nt) o[nt] = f32x4{0.f, 0.f, 0.f, 0.f};
    float lrun = 0.f;

    const int T  = 2 * (qb + 1);                   // total chunks for this q-block
    const int sz = (T + 3) >> 2;
    const int c0 = slice * sz;
    const int c1 = (c0 + sz < T) ? (c0 + sz) : T;
    const int nch = c1 - c0;                        // chunks for this block
    const int nin = (nch + 1) >> 1;                 // 2-chunk intervals
    const bool tail_odd = (nch & 1) != 0;
    const int swz = (lr & 7) << 3;

    // stage one interval (up to 2 chunks) into buffer `buf`
    auto stage_pair = [&](int buf, int j) {
        #pragma unroll
        for (int jj = 0; jj < 2; ++jj) {
            int ci = c0 + 2 * j + jj;
            if (ci < c1) {
                const unsigned short* gk = Kp + (size_t)ci * 64 * HD + w * 512 + lane * 8;
                const unsigned short* gv = Vp + (size_t)ci * 4096 + w * 512 + lane * 8;
                __builtin_amdgcn_global_load_lds(
                    (const __attribute__((address_space(1))) void*)gk,
                    (__attribute__((address_space(3))) void*)(ldsK + buf * 8192 + jj * 4096 + w * 512), 16, 0, 0);
                __builtin_amdgcn_global_load_lds(
                    (const __attribute__((address_space(1))) void*)gv,
                    (__attribute__((address_space(3))) void*)(ldsV + buf * 8192 + jj * 4096 + w * 512), 16, 0, 0);
            }
        }
    };

    if (nch > 0) {
        stage_pair(0, 0);
        for (int j = 0; j < nin; ++j) {
            if (j + 1 < nin) stage_pair((j + 1) & 1, j + 1);
            // wait for interval j's loads; remaining = loads of intervals beyond j
            if (j + 1 < nin) {
                if (tail_odd && (j + 2 == nin)) asm volatile("s_waitcnt vmcnt(2)" ::: "memory");
                else                            asm volatile("s_waitcnt vmcnt(4)" ::: "memory");
            } else {
                asm volatile("s_waitcnt vmcnt(0)" ::: "memory");
            }
            __builtin_amdgcn_sched_barrier(0);
            __builtin_amdgcn_s_barrier();

            #pragma unroll
            for (int jj = 0; jj < 2; ++jj) {
                const int ci = c0 + 2 * j + jj;
                if (ci < c1) {
                    const int kvb = ci * 64;
                    const int bufo = ((j & 1) * 2 + jj) * 4096;
                    if (kvb <= qwmax) {
                        f32x4 s0 = f32x4{0.f, 0.f, 0.f, 0.f};
                        f32x4 s1 = f32x4{0.f, 0.f, 0.f, 0.f};
                        f32x4 s2 = f32x4{0.f, 0.f, 0.f, 0.f};
                        f32x4 s3 = f32x4{0.f, 0.f, 0.f, 0.f};
                        {
                            short8 ka0 = *(const short8*)&ldsK[bufo + (0 * 16 + lr) * 64 + ((lg * 8)      ^ swz)];
                            short8 kb0 = *(const short8*)&ldsK[bufo + (0 * 16 + lr) * 64 + ((lg * 8 + 32) ^ swz)];
                            short8 ka1 = *(const short8*)&ldsK[bufo + (1 * 16 + lr) * 64 + ((lg * 8)      ^ swz)];
                            short8 kb1 = *(const short8*)&ldsK[bufo + (1 * 16 + lr) * 64 + ((lg * 8 + 32) ^ swz)];
                            short8 ka2 = *(const short8*)&ldsK[bufo + (2 * 16 + lr) * 64 + ((lg * 8)      ^ swz)];
                            short8 kb2 = *(const short8*)&ldsK[bufo + (2 * 16 + lr) * 64 + ((lg * 8 + 32) ^ swz)];
                            short8 ka3 = *(const short8*)&ldsK[bufo + (3 * 16 + lr) * 64 + ((lg * 8)      ^ swz)];
                            short8 kb3 = *(const short8*)&ldsK[bufo + (3 * 16 + lr) * 64 + ((lg * 8 + 32) ^ swz)];
                            s0 = __builtin_amdgcn_mfma_f32_16x16x32_bf16(ka0, qf0, s0, 0, 0, 0);
                            s0 = __builtin_amdgcn_mfma_f32_16x16x32_bf16(kb0, qf1, s0, 0, 0, 0);
                            s1 = __builtin_amdgcn_mfma_f32_16x16x32_bf16(ka1, qf0, s1, 0, 0, 0);
                            s1 = __builtin_amdgcn_mfma_f32_16x16x32_bf16(kb1, qf1, s1, 0, 0, 0);
                            s2 = __builtin_amdgcn_mfma_f32_16x16x32_bf16(ka2, qf0, s2, 0, 0, 0);
                            s2 = __builtin_amdgcn_mfma_f32_16x16x32_bf16(kb2, qf1, s2, 0, 0, 0);
                            s3 = __builtin_amdgcn_mfma_f32_16x16x32_bf16(ka3, qf0, s3, 0, 0, 0);
                            s3 = __builtin_amdgcn_mfma_f32_16x16x32_bf16(kb3, qf1, s3, 0, 0, 0);
                        }

                        if (kvb + 63 > qrow0) {          // mask if chunk passes FIRST row
                            const int qg = qrow0 + lr;
                            #pragma unroll
                            for (int r = 0; r < 4; ++r) {
                                int ky = kvb + lg * 4 + r;
                                if (ky      > qg) s0[r] = -1e30f;
                                if (ky + 16 > qg) s1[r] = -1e30f;
                                if (ky + 32 > qg) s2[r] = -1e30f;
                                if (ky + 48 > qg) s3[r] = -1e30f;
                            }
                        }

                        float p0[4], p1[4], p2[4], p3[4];
                        #pragma unroll
                        for (int r = 0; r < 4; ++r) {
                            p0[r] = exp2f(s0[r]);
                            p1[r] = exp2f(s1[r]);
                            p2[r] = exp2f(s2[r]);
                            p3[r] = exp2f(s3[r]);
                        }
                        lrun += ((p0[0] + p0[1]) + (p0[2] + p0[3])) + ((p1[0] + p1[1]) + (p1[2] + p1[3]))
                              + ((p2[0] + p2[1]) + (p2[2] + p2[3])) + ((p3[0] + p3[1]) + (p3[2] + p3[3]));

                        uint4v ua, ub;
                        asm("v_cvt_pk_bf16_f32 %0, %1, %2" : "=v"(ua[0]) : "v"(p0[0]), "v"(p0[1]));
                        asm("v_cvt_pk_bf16_f32 %0, %1, %2" : "=v"(ua[1]) : "v"(p0[2]), "v"(p0[3]));
                        asm("v_cvt_pk_bf16_f32 %0, %1, %2" : "=v"(ua[2]) : "v"(p1[0]), "v"(p1[1]));
                        asm("v_cvt_pk_bf16_f32 %0, %1, %2" : "=v"(ua[3]) : "v"(p1[2]), "v"(p1[3]));
                        asm("v_cvt_pk_bf16_f32 %0, %1, %2" : "=v"(ub[0]) : "v"(p2[0]), "v"(p2[1]));
                        asm("v_cvt_pk_bf16_f32 %0, %1, %2" : "=v"(ub[1]) : "v"(p2[2]), "v"(p2[3]));
                        asm("v_cvt_pk_bf16_f32 %0, %1, %2" : "=v"(ub[2]) : "v"(p3[0]), "v"(p3[1]));
                        asm("v_cvt_pk_bf16_f32 %0, %1, %2" : "=v"(ub[3]) : "v"(p3[2]), "v"(p3[3]));
                        short8 pba = *(short8*)&ua;      // keys kvb..kvb+31
                        short8 pbb = *(short8*)&ub;      // keys kvb+32..kvb+63

                        short8 va0 = *(const short8*)&ldsV[bufo + (0 * 16 + lr) * 64 + ((lg * 8)      ^ swz)];
                        short8 vb0 = *(const short8*)&ldsV[bufo + (0 * 16 + lr) * 64 + ((lg * 8 + 32) ^ swz)];
                        short8 va1 = *(const short8*)&ldsV[bufo + (1 * 16 + lr) * 64 + ((lg * 8)      ^ swz)];
                        short8 vb1 = *(const short8*)&ldsV[bufo + (1 * 16 + lr) * 64 + ((lg * 8 + 32) ^ swz)];
                        short8 va2 = *(const short8*)&ldsV[bufo + (2 * 16 + lr) * 64 + ((lg * 8)      ^ swz)];
                        short8 vb2 = *(const short8*)&ldsV[bufo + (2 * 16 + lr) * 64 + ((lg * 8 + 32) ^ swz)];
                        short8 va3 = *(const short8*)&ldsV[bufo + (3 * 16 + lr) * 64 + ((lg * 8)      ^ swz)];
                        short8 vb3 = *(const short8*)&ldsV[bufo + (3 * 16 + lr) * 64 + ((lg * 8 + 32) ^ swz)];
                        o[0] = __builtin_amdgcn_mfma_f32_16x16x32_bf16(va0, pba, o[0], 0, 0, 0);
                        o[1] = __builtin_amdgcn_mfma_f32_16x16x32_bf16(va1, pba, o[1], 0, 0, 0);
                        o[2] = __builtin_amdgcn_mfma_f32_16x16x32_bf16(va2, pba, o[2], 0, 0, 0);
                        o[3] = __builtin_amdgcn_mfma_f32_16x16x32_bf16(va3, pba, o[3], 0, 0, 0);
                        o[0] = __builtin_amdgcn_mfma_f32_16x16x32_bf16(vb0, pbb, o[0], 0, 0, 0);
                        o[1] = __builtin_amdgcn_mfma_f32_16x16x32_bf16(vb1, pbb, o[1], 0, 0, 0);
                        o[2] = __builtin_amdgcn_mfma_f32_16x16x32_bf16(vb2, pbb, o[2], 0, 0, 0);
                        o[3] = __builtin_amdgcn_mfma_f32_16x16x32_bf16(vb3, pbb, o[3], 0, 0, 0);
                    }
                }
            }
            __builtin_amdgcn_s_barrier();   // readers of buf j&1 done before reuse
        }
    }

    // ---- per-q l across lane groups (exact: all terms share m=0)
    lrun += __shfl_xor(lrun, 16);
    lrun += __shfl_xor(lrun, 32);

    // ---- write slice partials: o[nt][r] = O[q=lr][d = nt*16+lg*4+r]
    const size_t prow = (((size_t)slice * 4 + b) * 32 + qb) * 128 + w * 16 + lr;
    float* po = part_o + prow * 64;
    #pragma unroll
    for (int nt = 0; nt < 4; ++nt)
        *(f32x4*)(po + nt * 16 + lg * 4) = o[nt];
    if (lg == 0) part_l[prow] = lrun;
}

// ---------------------------------------------------------------------------
// Merge: out = (sum_s o_s) / (sum_s l_s) over 4 slices.
// ---------------------------------------------------------------------------
__global__ __launch_bounds__(256) void merge_kernel(
        const float* __restrict__ part_o, const float* __restrict__ part_l,
        float* __restrict__ out) {
    int idx = blockIdx.x * 256 + threadIdx.x;    // 0..262143
    int d4  = (idx & 15) * 4;
    int row = idx >> 4;                           // 0..16383 == b*4096 + q
    f32x4 a = f32x4{0.f, 0.f, 0.f, 0.f};
    float L = 0.f;
    #pragma unroll
    for (int s = 0; s < 4; ++s) {
        f32x4 p = *(const f32x4*)(part_o + ((size_t)s * 16384 + row) * 64 + d4);
        a[0] += p[0]; a[1] += p[1]; a[2] += p[2]; a[3] += p[3];
        L += part_l[s * 16384 + row];
    }
    float inv = 1.0f / L;
    f32x4 r;
    r[0] = a[0] * inv;
    r[1] = a[1] * inv;
    r[2] = a[2] * inv;
    r[3] = a[3] * inv;
    *(f32x4*)(out + (size_t)row * 64 + d4) = r;
}

// ---------------------------------------------------------------------------
extern "C" void kernel_launch(void* const* d_in, const int* in_sizes, int n_in,
                              void* d_out, int out_size, void* d_ws, size_t ws_size,
                              hipStream_t stream) {
    const float* H  = (const float*)d_in[0];
    const float* Wq = (const float*)d_in[1];
    const float* Wk = (const float*)d_in[2];
    const float* Wv = (const float*)d_in[3];
    float* out = (float*)d_out;

    // ws (bf16): Qb[1M] | Kb[1M] | Vt[1M] | Wt[196608]
    //   then (f32): part_o[4*16384*64] (16 MB) | part_l[4*16384] (256 KB)
    unsigned short* Qb = (unsigned short*)d_ws;
    unsigned short* Kb = Qb + (size_t)NB * SEQ * HD;
    unsigned short* Vt = Kb + (size_t)NB * SEQ * HD;
    unsigned short* Wt = Vt + (size_t)NB * SEQ * HD;
    float* part_o = (float*)(Wt + 3 * 65536);
    float* part_l = part_o + (size_t)4 * 16384 * 64;

    wprep_kernel<<<768, 256, 0, stream>>>(Wq, Wk, Wv, Wt);
    qkv_kernel<<<NB * SEQ / 64, 512, 0, stream>>>(H, Wt, Qb, Kb, Vt);
    attn_kernel<<<512, 512, 0, stream>>>(Qb, Kb, Vt, part_o, part_l);
    merge_kernel<<<1024, 256, 0, stream>>>(part_o, part_l, out);
}